// Round 7
// baseline (273.090 us; speedup 1.0000x reference)
//
#include <hip/hip_runtime.h>

typedef __attribute__((ext_vector_type(8))) short bf16x8;
typedef __attribute__((ext_vector_type(8))) _Float16 f16x8;
typedef __attribute__((ext_vector_type(2))) _Float16 f16x2;
typedef __attribute__((ext_vector_type(4))) float f32x4;
typedef __attribute__((ext_vector_type(16))) float f32x16;
typedef __attribute__((ext_vector_type(2))) unsigned int u32x2;

__device__ __forceinline__ unsigned short f2bf(float f) {
  union { float f; unsigned int i; } v;
  v.f = f;
  unsigned int r = v.i + 0x7FFFu + ((v.i >> 16) & 1u);  // RNE
  return (unsigned short)(r >> 16);
}

__device__ __forceinline__ f16x2 cvt_pk(float a, float b) {
  return __builtin_bit_cast(f16x2, __builtin_amdgcn_cvt_pkrtz(a, b));
}

__device__ __forceinline__ unsigned as_u32(f16x2 x) {
  return __builtin_bit_cast(unsigned int, x);
}
__device__ __forceinline__ f16x2 as_f16x2(unsigned x) {
  return __builtin_bit_cast(f16x2, x);
}

// permlane32_swap: ret.x[l<32]=a[l], ret.x[l>=32]=b[l-32];
//                  ret.y[l<32]=a[l+32], ret.y[l>=32]=b[l].
#if __has_builtin(__builtin_amdgcn_permlane32_swap)
__device__ __forceinline__ u32x2 plswap(unsigned a, unsigned b) {
  return __builtin_amdgcn_permlane32_swap(a, b, false, false);
}
#else
__device__ __forceinline__ u32x2 plswap(unsigned a, unsigned b) {
  unsigned pa = (unsigned)__shfl_xor((int)a, 32);
  unsigned pb = (unsigned)__shfl_xor((int)b, 32);
  int hi = (int)(threadIdx.x & 32);
  u32x2 r;
  r.x = hi ? pb : a;
  r.y = hi ? b : pa;
  return r;
}
#endif

__device__ __forceinline__ f16x8 pack4(f16x2 a, f16x2 b, f16x2 c, f16x2 d) {
  union { f16x2 h[4]; f16x8 v; } u;
  u.h[0] = a; u.h[1] = b; u.h[2] = c; u.h[3] = d;
  return u.v;
}

// async global->LDS, 16B/lane. LDS dst = wave-uniform base + lane*16.
__device__ __forceinline__ void gl_lds16(const unsigned short* g, unsigned short* l) {
  __builtin_amdgcn_global_load_lds(
      (const __attribute__((address_space(1))) unsigned int*)g,
      (__attribute__((address_space(3))) unsigned int*)l, 16, 0, 0);
}

// e^x on [-1,1], Chebyshev-truncated degree 5 (abs err ~5e-5), packed f16.
__device__ __forceinline__ f16x2 exp_poly(f16x2 x) {
  const f16x2 a5 = {(_Float16)0.00868682f, (_Float16)0.00868682f};
  const f16x2 a4 = {(_Float16)0.04379392f, (_Float16)0.04379392f};
  const f16x2 a3 = {(_Float16)0.16648887f, (_Float16)0.16648887f};
  const f16x2 a2 = {(_Float16)0.49919676f, (_Float16)0.49919676f};
  const f16x2 a1 = {(_Float16)1.00002229f, (_Float16)1.00002229f};
  const f16x2 a0 = {(_Float16)1.00004478f, (_Float16)1.00004478f};
#if __has_builtin(__builtin_elementwise_fma)
  f16x2 r = a5;
  r = __builtin_elementwise_fma(r, x, a4);
  r = __builtin_elementwise_fma(r, x, a3);
  r = __builtin_elementwise_fma(r, x, a2);
  r = __builtin_elementwise_fma(r, x, a1);
  r = __builtin_elementwise_fma(r, x, a0);
#else
  f16x2 r = a5;
  r = r * x + a4;
  r = r * x + a3;
  r = r * x + a2;
  r = r * x + a1;
  r = r * x + a0;
#endif
  return r;
}

// ---------------- fp32 -> bf16 convert to FRAGMENT-MAJOR layout ----------------
// (16x16 fragment layout for the three GEMMs; unchanged)
__global__ __launch_bounds__(256) void cvt_all(
    const float* __restrict__ x, const float* __restrict__ wq,
    const float* __restrict__ wkv, const float* __restrict__ wo,
    unsigned short* __restrict__ xf, unsigned short* __restrict__ wqf,
    unsigned short* __restrict__ wkvf, unsigned short* __restrict__ wof) {
  int b = blockIdx.x;
  const float* in;
  unsigned short* out;
  int i;
  if (b < 8192) { in = x; out = xf; i = b * 256 + threadIdx.x; }
  else if (b < 8448) { in = wq; out = wqf; i = (b - 8192) * 256 + threadIdx.x; }
  else if (b < 8704) { in = wkv; out = wkvf; i = (b - 8448) * 256 + threadIdx.x; }
  else { in = wo; out = wof; i = (b - 8704) * 256 + threadIdx.x; }
  float4 v = ((const float4*)in)[i];
  int f = i << 2;
  int row = f >> 9, c = f & 511;
  long off = ((((long)(row >> 7) * 8 + (c >> 6)) * 16 + ((row >> 4) & 7) * 2 +
               ((c >> 5) & 1)) * 64 + ((c >> 3) & 3) * 16 + (row & 15)) * 8 + (c & 7);
  ushort4 o;
  o.x = f2bf(v.x);
  o.y = f2bf(v.y);
  o.z = f2bf(v.z);
  o.w = f2bf(v.w);
  *(ushort4*)(out + off) = o;
}

// ---------------- fused Q + KV projection GEMM (fragment-major in) ----------------
// y<4 -> Q half (Qn bf16 normalized, row-major).
// y>=4 -> KV half: Kf = 32x32x16 A-fragment-major (normalized bf16),
//                  Vf = 32x32x16 B-fragment-major (f16, V[k][d]).
// Kf slots per kt: slot = kk*4 + dd   (kk=k>>5, dd=d>>4)
//   lane = (k&31) | (((d>>3)&1)<<5), e = d&7
// Vf slots per kt: slot = dt*4 + ksub (dt=d>>5, ksub=k>>4)
//   lane = (d&31) | (((k>>3)&1)<<5), e = k&7
__global__ __launch_bounds__(256) void gemm_qkv(
    const unsigned short* __restrict__ xf, const unsigned short* __restrict__ Wqf,
    const unsigned short* __restrict__ Wkvf, const float* __restrict__ bq,
    const float* __restrict__ bkv, unsigned short* __restrict__ Qn,
    unsigned short* __restrict__ Kf, unsigned short* __restrict__ Vf) {
  __shared__ __attribute__((aligned(16))) unsigned short lA[16 * 512];
  __shared__ __attribute__((aligned(16))) unsigned short lB[16 * 512];
  const int isKV = (int)(blockIdx.y >> 2);
  const unsigned short* Btf = isKV ? Wkvf : Wqf;
  const float* bias = isKV ? bkv : bq;
  const int tid = threadIdx.x;
  const int lane = tid & 63;
  const int quad = lane >> 4, m16 = lane & 15;
  const int w = tid >> 6;
  const int wm = w >> 1, wn = w & 1;
  const long mb = (long)blockIdx.x * 128;
  const int nt = (int)(blockIdx.y & 3);
  const long nb = (long)nt * 128;
  f32x4 acc[4][4];
#pragma unroll
  for (int i = 0; i < 4; i++)
#pragma unroll
    for (int j = 0; j < 4; j++) acc[i][j] = (f32x4){0.f, 0.f, 0.f, 0.f};

  for (int kb = 0; kb < 8; kb++) {
    __syncthreads();
    {
      const unsigned short* gA =
          xf + (((long)blockIdx.x * 8 + kb) * 16 + 4 * w) * 512 + lane * 8;
      gl_lds16(gA, &lA[(4 * w + 0) * 512]);
      gl_lds16(gA + 512, &lA[(4 * w + 1) * 512]);
      gl_lds16(gA + 1024, &lA[(4 * w + 2) * 512]);
      gl_lds16(gA + 1536, &lA[(4 * w + 3) * 512]);
      const unsigned short* gB =
          Btf + (((long)nt * 8 + kb) * 16 + 4 * w) * 512 + lane * 8;
      gl_lds16(gB, &lB[(4 * w + 0) * 512]);
      gl_lds16(gB + 512, &lB[(4 * w + 1) * 512]);
      gl_lds16(gB + 1024, &lB[(4 * w + 2) * 512]);
      gl_lds16(gB + 1536, &lB[(4 * w + 3) * 512]);
    }
    __syncthreads();
#pragma unroll
    for (int ks = 0; ks < 2; ks++) {
      bf16x8 af[4], bfr[4];
#pragma unroll
      for (int i = 0; i < 4; i++)
        af[i] = *(const bf16x8*)&lA[(((wm * 4 + i) << 1) | ks) * 512 + lane * 8];
#pragma unroll
      for (int j = 0; j < 4; j++)
        bfr[j] = *(const bf16x8*)&lB[(((wn * 4 + j) << 1) | ks) * 512 + lane * 8];
#pragma unroll
      for (int i = 0; i < 4; i++)
#pragma unroll
        for (int j = 0; j < 4; j++)
          acc[i][j] =
              __builtin_amdgcn_mfma_f32_16x16x32_bf16(af[i], bfr[j], acc[i][j], 0, 0, 0);
    }
  }
  const int h = (int)(nb >> 6) + wn;  // head is constant per wave-column
#pragma unroll
  for (int i = 0; i < 4; i++) {
    long row0 = mb + wm * 64 + i * 16 + quad * 4;
    float bb[4], val[4][4], inv[4];
#pragma unroll
    for (int j = 0; j < 4; j++) {
      bb[j] = bias[nb + wn * 64 + j * 16 + m16];
#pragma unroll
      for (int r = 0; r < 4; r++) val[j][r] = acc[i][j][r] + bb[j];
    }
#pragma unroll
    for (int r = 0; r < 4; r++) {
      float s = val[0][r] * val[0][r] + val[1][r] * val[1][r] +
                val[2][r] * val[2][r] + val[3][r] * val[3][r];
      s += __shfl_xor(s, 1);
      s += __shfl_xor(s, 2);
      s += __shfl_xor(s, 4);
      s += __shfl_xor(s, 8);
      inv[r] = 1.0f / fmaxf(sqrtf(s), 1e-12f);
    }
    if (!isKV) {
#pragma unroll
      for (int r = 0; r < 4; r++)
#pragma unroll
        for (int j = 0; j < 4; j++) {
          long col = nb + wn * 64 + j * 16 + m16;
          Qn[(row0 + r) * 512 + col] = f2bf(val[j][r] * inv[r]);
        }
    } else {
      const int bm2 = (int)(row0 >> 11);
      const int gq = bm2 * 8 + h;
      const int kt = (int)((row0 & 2047) >> 6);
      const long tb = ((long)gq * 32 + kt) * 8;
      // here k (seq within tile) = i*16 + quad*4 + r,  d (head dim) = j*16 + m16
      // Kf (A-frag): slot=(i>>1)*4+j; lane=((i&1)*16+quad*4+r)|((m16>>3)<<5); e=m16&7
#pragma unroll
      for (int j = 0; j < 4; j++) {
        long kb0 = (tb + (i >> 1) * 4 + j) * 512 +
                   ((((i & 1) * 16 + quad * 4) | ((m16 >> 3) << 5)) * 8) + (m16 & 7);
#pragma unroll
        for (int r = 0; r < 4; r++) Kf[kb0 + r * 8] = f2bf(val[j][r] * inv[r]);
      }
      // Vf (B-frag): slot=(j>>1)*4+i; lane=((j&1)*16+m16)|((quad>>1)<<5); e=(quad&1)*4+r
#pragma unroll
      for (int j = 0; j < 4; j++) {
        long vo = (tb + (j >> 1) * 4 + i) * 512 +
                  ((((j & 1) * 16 + m16) | ((quad >> 1) << 5)) * 8) + (quad & 1) * 4;
        f16x2 lo = cvt_pk(val[j][0], val[j][1]);
        f16x2 hi2 = cvt_pk(val[j][2], val[j][3]);
        uint2 pk = make_uint2(__builtin_bit_cast(unsigned int, lo),
                              __builtin_bit_cast(unsigned int, hi2));
        *(uint2*)(Vf + vo) = pk;
      }
    }
  }
}

// ---------------- output projection GEMM (fragment-major in, f32 out) ----------------
__global__ __launch_bounds__(256) void gemm_o(
    const unsigned short* __restrict__ Af, const unsigned short* __restrict__ Btf,
    const float* __restrict__ bias, float* __restrict__ Cout) {
  __shared__ __attribute__((aligned(16))) unsigned short lA[16 * 512];
  __shared__ __attribute__((aligned(16))) unsigned short lB[16 * 512];
  const int tid = threadIdx.x;
  const int lane = tid & 63;
  const int quad = lane >> 4, m16 = lane & 15;
  const int w = tid >> 6;
  const int wm = w >> 1, wn = w & 1;
  const long mb = (long)blockIdx.x * 128;
  const int nt = (int)blockIdx.y;
  const long nb = (long)nt * 128;
  f32x4 acc[4][4];
#pragma unroll
  for (int i = 0; i < 4; i++)
#pragma unroll
    for (int j = 0; j < 4; j++) acc[i][j] = (f32x4){0.f, 0.f, 0.f, 0.f};

  for (int kb = 0; kb < 8; kb++) {
    __syncthreads();
    {
      const unsigned short* gA =
          Af + (((long)blockIdx.x * 8 + kb) * 16 + 4 * w) * 512 + lane * 8;
      gl_lds16(gA, &lA[(4 * w + 0) * 512]);
      gl_lds16(gA + 512, &lA[(4 * w + 1) * 512]);
      gl_lds16(gA + 1024, &lA[(4 * w + 2) * 512]);
      gl_lds16(gA + 1536, &lA[(4 * w + 3) * 512]);
      const unsigned short* gB =
          Btf + (((long)nt * 8 + kb) * 16 + 4 * w) * 512 + lane * 8;
      gl_lds16(gB, &lB[(4 * w + 0) * 512]);
      gl_lds16(gB + 512, &lB[(4 * w + 1) * 512]);
      gl_lds16(gB + 1024, &lB[(4 * w + 2) * 512]);
      gl_lds16(gB + 1536, &lB[(4 * w + 3) * 512]);
    }
    __syncthreads();
#pragma unroll
    for (int ks = 0; ks < 2; ks++) {
      bf16x8 af[4], bfr[4];
#pragma unroll
      for (int i = 0; i < 4; i++)
        af[i] = *(const bf16x8*)&lA[(((wm * 4 + i) << 1) | ks) * 512 + lane * 8];
#pragma unroll
      for (int j = 0; j < 4; j++)
        bfr[j] = *(const bf16x8*)&lB[(((wn * 4 + j) << 1) | ks) * 512 + lane * 8];
#pragma unroll
      for (int i = 0; i < 4; i++)
#pragma unroll
        for (int j = 0; j < 4; j++)
          acc[i][j] =
              __builtin_amdgcn_mfma_f32_16x16x32_bf16(af[i], bfr[j], acc[i][j], 0, 0, 0);
    }
  }
#pragma unroll
  for (int i = 0; i < 4; i++) {
    long row0 = mb + wm * 64 + i * 16 + quad * 4;
#pragma unroll
    for (int j = 0; j < 4; j++) {
      long col = nb + wn * 64 + j * 16 + m16;
      float bb = bias[col];
#pragma unroll
      for (int r = 0; r < 4; r++) Cout[(row0 + r) * 512 + col] = acc[i][j][r] + bb;
    }
  }
}

// ---------------- cosine attention (barrier-free direct-global, 32x32 MFMA) ----------------
// Rounds 3-6: four different sync schedules all pinned at ~89.5us with no pipe
// above 47% -> the wall is barrier-lockstep phase bunching, not any resource.
// Fix: fragment-major Kf/Vf makes the LDS stage an identity copy, so read
// fragments DIRECTLY from global (L2-resident by the XCD-set grid decode;
// the 4 waves of a block run in-phase and share each kt's 16 KB through L1).
// No LDS, no barriers: waves free-run and the VALU/MFMA/VMEM pipes overlap
// across waves instead of bursting in lockstep.
// VALU diet vs r6: zero-C first QK MFMA (no per-kt acc init); li via
// ones-MFMA (kills the 32-deep serial fdot2 chain AND the epilogue shuffle
// redistribution -- caccl rows align exactly with cacc rows).
// kk-half processing keeps transient VGPR low (target ~150 -> 3 waves/SIMD).
__global__ __launch_bounds__(256, 3) void attn_cos(
    const unsigned short* __restrict__ Qn, const unsigned short* __restrict__ Kf,
    const unsigned short* __restrict__ Vf, unsigned short* __restrict__ ctxf) {
  const int id = (int)blockIdx.x;
  const int g = ((id >> 7) << 3) | (id & 7);  // 0..63 (8 distinct groups/XCD
  const int qt = (id >> 3) & 15;              //  under both assignment models)
  const int bm = g >> 3, h = g & 7;
  const int tid = threadIdx.x;
  const int lane = tid & 63;
  const int l31 = lane & 31, hi = lane >> 5;
  const int w = tid >> 6;  // 0..3
  const long qrow0 = (long)bm * 2048 + qt * 128 + w * 32;
  const int colbase = h * 64;

  // Q B-fragments (32x32x16): col=q=l31, k-elem = d = dd*16 + hi*8 + e
  bf16x8 qf[4];
#pragma unroll
  for (int dd = 0; dd < 4; dd++)
    qf[dd] = *(const bf16x8*)(Qn + (qrow0 + l31) * 512 + colbase + dd * 16 + hi * 8);

  f32x16 cacc[2];
  f32x16 caccl;  // li via ones-MFMA: D[q][*] = sum_k P[q][k], rows align w/ cacc
#pragma unroll
  for (int e = 0; e < 16; e++) { cacc[0][e] = 0.f; cacc[1][e] = 0.f; caccl[e] = 0.f; }
  const f16x8 onesv = {(_Float16)1.0f, (_Float16)1.0f, (_Float16)1.0f, (_Float16)1.0f,
                       (_Float16)1.0f, (_Float16)1.0f, (_Float16)1.0f, (_Float16)1.0f};
  const f32x16 zv = {};  // zero-C for the first QK MFMA of each half

  const unsigned short* baseK = Kf + ((long)g * 32) * 8 * 512 + lane * 8;
  const unsigned short* baseV = Vf + ((long)g * 32) * 8 * 512 + lane * 8;

  for (int kt = 0; kt < 32; ++kt) {
    const unsigned short* pK = baseK + (long)kt * (8 * 512);
    const unsigned short* pV = baseV + (long)kt * (8 * 512);
#pragma unroll
    for (int kk = 0; kk < 2; kk++) {
      // direct global fragment loads (identical addressing to the old LDS
      // path -- fragment-major layout). V issued early, consumed after exp.
      bf16x8 kf[4];
      f16x8 vf[2][2];
#pragma unroll
      for (int dd = 0; dd < 4; dd++)
        kf[dd] = *(const bf16x8*)(pK + (kk * 4 + dd) * 512);
#pragma unroll
      for (int s = 0; s < 2; s++)
#pragma unroll
        for (int dt = 0; dt < 2; dt++)
          vf[s][dt] = *(const f16x8*)(pV + (dt * 4 + kk * 2 + s) * 512);

      // ---- QK^T half (32x32x16): rows = k-seq of this half, cols = q ----
      f32x16 sacc = __builtin_amdgcn_mfma_f32_32x32x16_bf16(kf[0], qf[0], zv, 0, 0, 0);
#pragma unroll
      for (int dd = 1; dd < 4; dd++)
        sacc = __builtin_amdgcn_mfma_f32_32x32x16_bf16(kf[dd], qf[dd], sacc, 0, 0, 0);

      // ---- exp (packed f16); k(reg) = (reg&3)+8*(reg>>2)+4*hi ----
      f16x2 pe[8];
#pragma unroll
      for (int t = 0; t < 8; t++)
        pe[t] = exp_poly(cvt_pk(sacc[2 * t], sacc[2 * t + 1]));

      // ---- PA via permlane32_swap + PV + ones-li (32x32x16 f16) ----
#pragma unroll
      for (int s = 0; s < 2; s++) {
        u32x2 r0 = plswap(as_u32(pe[4 * s + 0]), as_u32(pe[4 * s + 2]));
        u32x2 r1 = plswap(as_u32(pe[4 * s + 1]), as_u32(pe[4 * s + 3]));
        f16x8 pa = pack4(as_f16x2(r0.x), as_f16x2(r1.x), as_f16x2(r0.y), as_f16x2(r1.y));
        cacc[0] = __builtin_amdgcn_mfma_f32_32x32x16_f16(pa, vf[s][0], cacc[0], 0, 0, 0);
        cacc[1] = __builtin_amdgcn_mfma_f32_32x32x16_f16(pa, vf[s][1], cacc[1], 0, 0, 0);
        caccl = __builtin_amdgcn_mfma_f32_32x32x16_f16(pa, onesv, caccl, 0, 0, 0);
      }
    }
  }

  // caccl rows == cacc rows (same C layout) -> no shuffles needed at all
  float linv[16];
#pragma unroll
  for (int r = 0; r < 16; r++) linv[r] = 1.0f / caccl[r];

  // epilogue: scalar scatter into the 16x16 FRAGMENT-MAJOR ctxf for gemm_o
#pragma unroll
  for (int dt = 0; dt < 2; dt++) {
    const int c = colbase + dt * 32 + l31;  // global feature col 0..511
    const long ckb = (long)(c >> 6);
    const int cbit = (c >> 5) & 1;
    const int lane16 = ((c >> 3) & 3) * 16;
    const int e = c & 7;
#pragma unroll
    for (int r = 0; r < 16; r++) {
      long row = qrow0 + (r & 3) + 8 * (r >> 2) + 4 * hi;
      long off = ((((row >> 7) * 8 + ckb) * 16 + ((row >> 4) & 7) * 2 + cbit) * 64 +
                  lane16 + (row & 15)) * 8 + e;
      ctxf[off] = f2bf(cacc[dt][r] * linv[r]);
    }
  }
}

extern "C" void kernel_launch(void* const* d_in, const int* in_sizes, int n_in,
                              void* d_out, int out_size, void* d_ws, size_t ws_size,
                              hipStream_t stream) {
  (void)in_sizes; (void)n_in; (void)out_size; (void)ws_size;
  const float* x = (const float*)d_in[0];
  const float* Wq = (const float*)d_in[1];
  const float* bq = (const float*)d_in[2];
  const float* Wkv = (const float*)d_in[3];
  const float* bkv = (const float*)d_in[4];
  const float* Wo = (const float*)d_in[5];
  const float* bo = (const float*)d_in[6];

  char* ws = (char*)d_ws;
  unsigned short* xf     = (unsigned short*)(ws);             // 16 MiB (reused as ctxf)
  unsigned short* Wqf    = (unsigned short*)(ws + 16777216);  // 512 KiB
  unsigned short* Wkvf   = (unsigned short*)(ws + 17301504);  // 512 KiB
  unsigned short* Wof    = (unsigned short*)(ws + 17825792);  // 512 KiB
  unsigned short* Qn_bf  = (unsigned short*)(ws + 18350080);  // 16 MiB
  unsigned short* Kf     = (unsigned short*)(ws + 35127296);  // 16 MiB
  unsigned short* Vf     = (unsigned short*)(ws + 51904512);  // 16 MiB
  unsigned short* ctxf   = xf;  // x dead after gemm_qkv

  cvt_all<<<8960, 256, 0, stream>>>(x, Wq, Wkv, Wo, xf, Wqf, Wkvf, Wof);

  gemm_qkv<<<dim3(128, 8), 256, 0, stream>>>(xf, Wqf, Wkvf, bq, bkv, Qn_bf, Kf, Vf);

  attn_cos<<<1024, 256, 0, stream>>>(Qn_bf, Kf, Vf, ctxf);

  gemm_o<<<dim3(128, 4), 256, 0, stream>>>(ctxf, Wof, bo, (float*)d_out);
}

// Round 8
// 267.128 us; speedup vs baseline: 1.0223x; 1.0223x over previous
//
#include <hip/hip_runtime.h>

typedef __attribute__((ext_vector_type(8))) short bf16x8;
typedef __attribute__((ext_vector_type(8))) _Float16 f16x8;
typedef __attribute__((ext_vector_type(2))) _Float16 f16x2;
typedef __attribute__((ext_vector_type(4))) float f32x4;
typedef __attribute__((ext_vector_type(16))) float f32x16;
typedef __attribute__((ext_vector_type(2))) unsigned int u32x2;

__device__ __forceinline__ unsigned short f2bf(float f) {
  union { float f; unsigned int i; } v;
  v.f = f;
  unsigned int r = v.i + 0x7FFFu + ((v.i >> 16) & 1u);  // RNE
  return (unsigned short)(r >> 16);
}

// 2x f32 -> packed bf16 (RNE) in ONE instruction; lo16 = a, hi16 = b.
__device__ __forceinline__ unsigned cvt_pk_bf16(float a, float b) {
  unsigned r;
  asm("v_cvt_pk_bf16_f32 %0, %1, %2" : "=v"(r) : "v"(a), "v"(b));
  return r;
}

__device__ __forceinline__ f16x2 cvt_pk(float a, float b) {
  return __builtin_bit_cast(f16x2, __builtin_amdgcn_cvt_pkrtz(a, b));
}

__device__ __forceinline__ unsigned as_u32(f16x2 x) {
  return __builtin_bit_cast(unsigned int, x);
}
__device__ __forceinline__ f16x2 as_f16x2(unsigned x) {
  return __builtin_bit_cast(f16x2, x);
}

// permlane32_swap: ret.x[l<32]=a[l], ret.x[l>=32]=b[l-32];
//                  ret.y[l<32]=a[l+32], ret.y[l>=32]=b[l].
#if __has_builtin(__builtin_amdgcn_permlane32_swap)
__device__ __forceinline__ u32x2 plswap(unsigned a, unsigned b) {
  return __builtin_amdgcn_permlane32_swap(a, b, false, false);
}
#else
__device__ __forceinline__ u32x2 plswap(unsigned a, unsigned b) {
  unsigned pa = (unsigned)__shfl_xor((int)a, 32);
  unsigned pb = (unsigned)__shfl_xor((int)b, 32);
  int hi = (int)(threadIdx.x & 32);
  u32x2 r;
  r.x = hi ? pb : a;
  r.y = hi ? b : pa;
  return r;
}
#endif

__device__ __forceinline__ f16x8 pack4(f16x2 a, f16x2 b, f16x2 c, f16x2 d) {
  union { f16x2 h[4]; f16x8 v; } u;
  u.h[0] = a; u.h[1] = b; u.h[2] = c; u.h[3] = d;
  return u.v;
}

// async global->LDS, 16B/lane. LDS dst = wave-uniform base + lane*16.
__device__ __forceinline__ void gl_lds16(const unsigned short* g, unsigned short* l) {
  __builtin_amdgcn_global_load_lds(
      (const __attribute__((address_space(1))) unsigned int*)g,
      (__attribute__((address_space(3))) unsigned int*)l, 16, 0, 0);
}

// e^x on [-1,1], Chebyshev-truncated degree 5 (abs err ~5e-5), packed f16.
__device__ __forceinline__ f16x2 exp_poly(f16x2 x) {
  const f16x2 a5 = {(_Float16)0.00868682f, (_Float16)0.00868682f};
  const f16x2 a4 = {(_Float16)0.04379392f, (_Float16)0.04379392f};
  const f16x2 a3 = {(_Float16)0.16648887f, (_Float16)0.16648887f};
  const f16x2 a2 = {(_Float16)0.49919676f, (_Float16)0.49919676f};
  const f16x2 a1 = {(_Float16)1.00002229f, (_Float16)1.00002229f};
  const f16x2 a0 = {(_Float16)1.00004478f, (_Float16)1.00004478f};
#if __has_builtin(__builtin_elementwise_fma)
  f16x2 r = a5;
  r = __builtin_elementwise_fma(r, x, a4);
  r = __builtin_elementwise_fma(r, x, a3);
  r = __builtin_elementwise_fma(r, x, a2);
  r = __builtin_elementwise_fma(r, x, a1);
  r = __builtin_elementwise_fma(r, x, a0);
#else
  f16x2 r = a5;
  r = r * x + a4;
  r = r * x + a3;
  r = r * x + a2;
  r = r * x + a1;
  r = r * x + a0;
#endif
  return r;
}

// ---------------- fused Q + KV projection GEMM (f32 inputs, inline cvt) ----------------
// cvt_all is GONE: A is staged from x (f32) and B from Wq/Wkv (f32) via
// reg-load + v_cvt_pk_bf16_f32 + ds_write_b128. LDS contents are byte-identical
// to the old fragment-major path: slot s, lane l holds
//   row = tilebase + (s>>1)*16 + (l&15), col = kb*64 + (s&1)*32 + (l>>4)*8 + e.
// Outputs unchanged: Qn bf16 row-major (normalized); Kf/Vf 32x32-fragment-major.
__global__ __launch_bounds__(256) void gemm_qkv(
    const float* __restrict__ X, const float* __restrict__ Wq,
    const float* __restrict__ Wkv, const float* __restrict__ bq,
    const float* __restrict__ bkv, unsigned short* __restrict__ Qn,
    unsigned short* __restrict__ Kf, unsigned short* __restrict__ Vf) {
  __shared__ __attribute__((aligned(16))) unsigned short lA[16 * 512];
  __shared__ __attribute__((aligned(16))) unsigned short lB[16 * 512];
  const int isKV = (int)(blockIdx.y >> 2);
  const float* Wt = isKV ? Wkv : Wq;
  const float* bias = isKV ? bkv : bq;
  const int tid = threadIdx.x;
  const int lane = tid & 63;
  const int quad = lane >> 4, m16 = lane & 15;
  const int w = tid >> 6;
  const int wm = w >> 1, wn = w & 1;
  const long mb = (long)blockIdx.x * 128;
  const int nt = (int)(blockIdx.y & 3);
  const long nb = (long)nt * 128;
  f32x4 acc[4][4];
#pragma unroll
  for (int i = 0; i < 4; i++)
#pragma unroll
    for (int j = 0; j < 4; j++) acc[i][j] = (f32x4){0.f, 0.f, 0.f, 0.f};

  for (int kb = 0; kb < 8; kb++) {
    __syncthreads();
    {
      float4 fa[4][2], fb[4][2];
#pragma unroll
      for (int t = 0; t < 4; t++) {
        const int s = 4 * w + t;
        const int col = kb * 64 + (s & 1) * 32 + quad * 8;
        const float* pa = X + (mb + (s >> 1) * 16 + m16) * 512 + col;
        fa[t][0] = *(const float4*)pa;
        fa[t][1] = *(const float4*)(pa + 4);
        const float* pb = Wt + (nb + (s >> 1) * 16 + m16) * 512 + col;
        fb[t][0] = *(const float4*)pb;
        fb[t][1] = *(const float4*)(pb + 4);
      }
#pragma unroll
      for (int t = 0; t < 4; t++) {
        const int s = 4 * w + t;
        uint4 ca, cb;
        ca.x = cvt_pk_bf16(fa[t][0].x, fa[t][0].y);
        ca.y = cvt_pk_bf16(fa[t][0].z, fa[t][0].w);
        ca.z = cvt_pk_bf16(fa[t][1].x, fa[t][1].y);
        ca.w = cvt_pk_bf16(fa[t][1].z, fa[t][1].w);
        *(uint4*)&lA[s * 512 + lane * 8] = ca;
        cb.x = cvt_pk_bf16(fb[t][0].x, fb[t][0].y);
        cb.y = cvt_pk_bf16(fb[t][0].z, fb[t][0].w);
        cb.z = cvt_pk_bf16(fb[t][1].x, fb[t][1].y);
        cb.w = cvt_pk_bf16(fb[t][1].z, fb[t][1].w);
        *(uint4*)&lB[s * 512 + lane * 8] = cb;
      }
    }
    __syncthreads();
#pragma unroll
    for (int ks = 0; ks < 2; ks++) {
      bf16x8 af[4], bfr[4];
#pragma unroll
      for (int i = 0; i < 4; i++)
        af[i] = *(const bf16x8*)&lA[(((wm * 4 + i) << 1) | ks) * 512 + lane * 8];
#pragma unroll
      for (int j = 0; j < 4; j++)
        bfr[j] = *(const bf16x8*)&lB[(((wn * 4 + j) << 1) | ks) * 512 + lane * 8];
#pragma unroll
      for (int i = 0; i < 4; i++)
#pragma unroll
        for (int j = 0; j < 4; j++)
          acc[i][j] =
              __builtin_amdgcn_mfma_f32_16x16x32_bf16(af[i], bfr[j], acc[i][j], 0, 0, 0);
    }
  }
  const int h = (int)(nb >> 6) + wn;  // head is constant per wave-column
#pragma unroll
  for (int i = 0; i < 4; i++) {
    long row0 = mb + wm * 64 + i * 16 + quad * 4;
    float bb[4], val[4][4], inv[4];
#pragma unroll
    for (int j = 0; j < 4; j++) {
      bb[j] = bias[nb + wn * 64 + j * 16 + m16];
#pragma unroll
      for (int r = 0; r < 4; r++) val[j][r] = acc[i][j][r] + bb[j];
    }
#pragma unroll
    for (int r = 0; r < 4; r++) {
      float s = val[0][r] * val[0][r] + val[1][r] * val[1][r] +
                val[2][r] * val[2][r] + val[3][r] * val[3][r];
      s += __shfl_xor(s, 1);
      s += __shfl_xor(s, 2);
      s += __shfl_xor(s, 4);
      s += __shfl_xor(s, 8);
      inv[r] = 1.0f / fmaxf(sqrtf(s), 1e-12f);
    }
    if (!isKV) {
#pragma unroll
      for (int r = 0; r < 4; r++)
#pragma unroll
        for (int j = 0; j < 4; j++) {
          long col = nb + wn * 64 + j * 16 + m16;
          Qn[(row0 + r) * 512 + col] = f2bf(val[j][r] * inv[r]);
        }
    } else {
      const int bm2 = (int)(row0 >> 11);
      const int gq = bm2 * 8 + h;
      const int kt = (int)((row0 & 2047) >> 6);
      const long tb = ((long)gq * 32 + kt) * 8;
      // k (seq within tile) = i*16 + quad*4 + r,  d (head dim) = j*16 + m16
      // Kf (A-frag): slot=(i>>1)*4+j; lane=((i&1)*16+quad*4+r)|((m16>>3)<<5); e=m16&7
#pragma unroll
      for (int j = 0; j < 4; j++) {
        long kb0 = (tb + (i >> 1) * 4 + j) * 512 +
                   ((((i & 1) * 16 + quad * 4) | ((m16 >> 3) << 5)) * 8) + (m16 & 7);
#pragma unroll
        for (int r = 0; r < 4; r++) Kf[kb0 + r * 8] = f2bf(val[j][r] * inv[r]);
      }
      // Vf (B-frag): slot=(j>>1)*4+i; lane=((j&1)*16+m16)|((quad>>1)<<5); e=(quad&1)*4+r
#pragma unroll
      for (int j = 0; j < 4; j++) {
        long vo = (tb + (j >> 1) * 4 + i) * 512 +
                  ((((j & 1) * 16 + m16) | ((quad >> 1) << 5)) * 8) + (quad & 1) * 4;
        f16x2 lo = cvt_pk(val[j][0], val[j][1]);
        f16x2 hi2 = cvt_pk(val[j][2], val[j][3]);
        uint2 pk = make_uint2(__builtin_bit_cast(unsigned int, lo),
                              __builtin_bit_cast(unsigned int, hi2));
        *(uint2*)(Vf + vo) = pk;
      }
    }
  }
}

// ---------------- output projection GEMM (A bf16 frag-major, B f32 + inline cvt) ----------------
__global__ __launch_bounds__(256) void gemm_o(
    const unsigned short* __restrict__ Af, const float* __restrict__ Wo,
    const float* __restrict__ bias, float* __restrict__ Cout) {
  __shared__ __attribute__((aligned(16))) unsigned short lA[16 * 512];
  __shared__ __attribute__((aligned(16))) unsigned short lB[16 * 512];
  const int tid = threadIdx.x;
  const int lane = tid & 63;
  const int quad = lane >> 4, m16 = lane & 15;
  const int w = tid >> 6;
  const int wm = w >> 1, wn = w & 1;
  const long mb = (long)blockIdx.x * 128;
  const int nt = (int)blockIdx.y;
  const long nb = (long)nt * 128;
  f32x4 acc[4][4];
#pragma unroll
  for (int i = 0; i < 4; i++)
#pragma unroll
    for (int j = 0; j < 4; j++) acc[i][j] = (f32x4){0.f, 0.f, 0.f, 0.f};

  for (int kb = 0; kb < 8; kb++) {
    __syncthreads();
    {
      // A: ctxf is already bf16 fragment-major (written by attn) -> async copy
      const unsigned short* gA =
          Af + (((long)blockIdx.x * 8 + kb) * 16 + 4 * w) * 512 + lane * 8;
      gl_lds16(gA, &lA[(4 * w + 0) * 512]);
      gl_lds16(gA + 512, &lA[(4 * w + 1) * 512]);
      gl_lds16(gA + 1024, &lA[(4 * w + 2) * 512]);
      gl_lds16(gA + 1536, &lA[(4 * w + 3) * 512]);
      // B: Wo f32 -> bf16 inline
      float4 fb[4][2];
#pragma unroll
      for (int t = 0; t < 4; t++) {
        const int s = 4 * w + t;
        const int col = kb * 64 + (s & 1) * 32 + quad * 8;
        const float* pb = Wo + (nb + (s >> 1) * 16 + m16) * 512 + col;
        fb[t][0] = *(const float4*)pb;
        fb[t][1] = *(const float4*)(pb + 4);
      }
#pragma unroll
      for (int t = 0; t < 4; t++) {
        const int s = 4 * w + t;
        uint4 cb;
        cb.x = cvt_pk_bf16(fb[t][0].x, fb[t][0].y);
        cb.y = cvt_pk_bf16(fb[t][0].z, fb[t][0].w);
        cb.z = cvt_pk_bf16(fb[t][1].x, fb[t][1].y);
        cb.w = cvt_pk_bf16(fb[t][1].z, fb[t][1].w);
        *(uint4*)&lB[s * 512 + lane * 8] = cb;
      }
    }
    __syncthreads();
#pragma unroll
    for (int ks = 0; ks < 2; ks++) {
      bf16x8 af[4], bfr[4];
#pragma unroll
      for (int i = 0; i < 4; i++)
        af[i] = *(const bf16x8*)&lA[(((wm * 4 + i) << 1) | ks) * 512 + lane * 8];
#pragma unroll
      for (int j = 0; j < 4; j++)
        bfr[j] = *(const bf16x8*)&lB[(((wn * 4 + j) << 1) | ks) * 512 + lane * 8];
#pragma unroll
      for (int i = 0; i < 4; i++)
#pragma unroll
        for (int j = 0; j < 4; j++)
          acc[i][j] =
              __builtin_amdgcn_mfma_f32_16x16x32_bf16(af[i], bfr[j], acc[i][j], 0, 0, 0);
    }
  }
#pragma unroll
  for (int i = 0; i < 4; i++) {
    long row0 = mb + wm * 64 + i * 16 + quad * 4;
#pragma unroll
    for (int j = 0; j < 4; j++) {
      long col = nb + wn * 64 + j * 16 + m16;
      float bb = bias[col];
#pragma unroll
      for (int r = 0; r < 4; r++) Cout[(row0 + r) * 512 + col] = acc[i][j][r] + bb;
    }
  }
}

// ---------------- cosine attention (r6 skeleton + VALU diet) ----------------
// Best-known structure (89.7us): triple-buffered gl_lds staging, counted
// vmcnt(2) + raw barrier, setprio on MFMA clusters, 32x32 MFMA, in-register P
// via permlane32_swap. This version adds: zero-C first QK MFMA (kills 32
// per-kt acc-init movs) and li via ones-MFMA (kills the 16-deep serial fdot2
// chain + all epilogue li shuffles; HW-validated in round 7).
__global__ __launch_bounds__(512, 4) void attn_cos(
    const unsigned short* __restrict__ Qn, const unsigned short* __restrict__ Kf,
    const unsigned short* __restrict__ Vf, unsigned short* __restrict__ ctxf) {
  __shared__ __attribute__((aligned(16))) unsigned short lK[3][8 * 512];   // 24 KB
  __shared__ __attribute__((aligned(16))) unsigned short lVt[3][8 * 512];  // 24 KB
  const int id = (int)blockIdx.x;
  const int g = ((id >> 6) << 3) | (id & 7);  // 0..63
  const int qt = (id >> 3) & 7;               // 0..7 (256-row tiles)
  const int bm = g >> 3, h = g & 7;
  const int tid = threadIdx.x;
  const int lane = tid & 63;
  const int l31 = lane & 31, hi = lane >> 5;
  const int w = tid >> 6;  // 0..7
  const long qrow0 = (long)bm * 2048 + qt * 256 + w * 32;
  const int colbase = h * 64;

  // Q B-fragments (32x32x16): col=q=l31, k-elem = d = dd*16 + hi*8 + e
  bf16x8 qf[4];
#pragma unroll
  for (int dd = 0; dd < 4; dd++)
    qf[dd] = *(const bf16x8*)(Qn + (qrow0 + l31) * 512 + colbase + dd * 16 + hi * 8);

  f32x16 cacc[2];
  f32x16 caccl;  // li via ones-MFMA: rows align exactly with cacc rows
#pragma unroll
  for (int e = 0; e < 16; e++) { cacc[0][e] = 0.f; cacc[1][e] = 0.f; caccl[e] = 0.f; }
  const f16x8 onesv = {(_Float16)1.0f, (_Float16)1.0f, (_Float16)1.0f, (_Float16)1.0f,
                       (_Float16)1.0f, (_Float16)1.0f, (_Float16)1.0f, (_Float16)1.0f};
  const f32x16 zv = {};  // zero-C for the first QK MFMA

#define STAGE(buf, ktn)                                                  \
  {                                                                      \
    const long tb_ = ((long)g * 32 + (ktn)) * 8;                         \
    gl_lds16(Kf + (tb_ + w) * 512 + lane * 8, &lK[(buf)][w * 512]);      \
    gl_lds16(Vf + (tb_ + w) * 512 + lane * 8, &lVt[(buf)][w * 512]);     \
  }

  // prologue: 2-deep prefetch. After vmcnt(2), buf0 landed (buf1 may be in flight).
  STAGE(0, 0);
  STAGE(1, 1);
  asm volatile("s_waitcnt vmcnt(2)" ::: "memory");
  __builtin_amdgcn_s_barrier();
  __builtin_amdgcn_sched_barrier(0);

  int cur = 0, nxt = 2;
  for (int kt = 0; kt < 32; ++kt) {
    // issue stage of kt+2 (wraps at the tail: harmless L2-hit refetch, keeps
    // the outstanding-load count uniform so vmcnt(2) is always correct)
    STAGE(nxt, (kt + 2) & 31);
    __builtin_amdgcn_sched_barrier(0);
    const unsigned short* bK = lK[cur];
    const unsigned short* bV = lVt[cur];

    // ---- QK^T (32x32x16), zero-C first MFMA: no per-kt acc init ----
    f32x16 sacc[2];
    __builtin_amdgcn_s_setprio(1);
    {
      bf16x8 k0 = *(const bf16x8*)&bK[(0 * 4 + 0) * 512 + lane * 8];
      bf16x8 k1 = *(const bf16x8*)&bK[(1 * 4 + 0) * 512 + lane * 8];
      sacc[0] = __builtin_amdgcn_mfma_f32_32x32x16_bf16(k0, qf[0], zv, 0, 0, 0);
      sacc[1] = __builtin_amdgcn_mfma_f32_32x32x16_bf16(k1, qf[0], zv, 0, 0, 0);
    }
#pragma unroll
    for (int dd = 1; dd < 4; dd++) {
      bf16x8 k0 = *(const bf16x8*)&bK[(0 * 4 + dd) * 512 + lane * 8];
      bf16x8 k1 = *(const bf16x8*)&bK[(1 * 4 + dd) * 512 + lane * 8];
      sacc[0] = __builtin_amdgcn_mfma_f32_32x32x16_bf16(k0, qf[dd], sacc[0], 0, 0, 0);
      sacc[1] = __builtin_amdgcn_mfma_f32_32x32x16_bf16(k1, qf[dd], sacc[1], 0, 0, 0);
    }
    __builtin_amdgcn_s_setprio(0);

    // ---- exp (packed f16); k(reg) = (reg&3)+8*(reg>>2)+4*hi ----
    f16x2 pe[2][8];
#pragma unroll
    for (int kk = 0; kk < 2; kk++)
#pragma unroll
      for (int t = 0; t < 8; t++)
        pe[kk][t] = exp_poly(cvt_pk(sacc[kk][2 * t], sacc[kk][2 * t + 1]));

    // ---- PA via permlane32_swap + PV + ones-li (32x32x16 f16) ----
    __builtin_amdgcn_s_setprio(1);
#pragma unroll
    for (int kk = 0; kk < 2; kk++)
#pragma unroll
      for (int s = 0; s < 2; s++) {
        u32x2 r0 = plswap(as_u32(pe[kk][4 * s + 0]), as_u32(pe[kk][4 * s + 2]));
        u32x2 r1 = plswap(as_u32(pe[kk][4 * s + 1]), as_u32(pe[kk][4 * s + 3]));
        f16x8 pa = pack4(as_f16x2(r0.x), as_f16x2(r1.x), as_f16x2(r0.y), as_f16x2(r1.y));
        const int ksub = kk * 2 + s;
        f16x8 v0 = *(const f16x8*)&bV[(0 * 4 + ksub) * 512 + lane * 8];
        f16x8 v1 = *(const f16x8*)&bV[(1 * 4 + ksub) * 512 + lane * 8];
        cacc[0] = __builtin_amdgcn_mfma_f32_32x32x16_f16(pa, v0, cacc[0], 0, 0, 0);
        cacc[1] = __builtin_amdgcn_mfma_f32_32x32x16_f16(pa, v1, cacc[1], 0, 0, 0);
        caccl = __builtin_amdgcn_mfma_f32_32x32x16_f16(pa, onesv, caccl, 0, 0, 0);
      }
    __builtin_amdgcn_s_setprio(0);

    // counted wait + RAW barrier: kt+1's stage landed, kt+2's stays in flight.
    asm volatile("s_waitcnt vmcnt(2) lgkmcnt(0)" ::: "memory");
    __builtin_amdgcn_sched_barrier(0);
    __builtin_amdgcn_s_barrier();
    __builtin_amdgcn_sched_barrier(0);
    cur = (cur == 2) ? 0 : cur + 1;
    nxt = (nxt == 2) ? 0 : nxt + 1;
  }
#undef STAGE

  // li: caccl rows == cacc rows -> no shuffles at all
  float linv[16];
#pragma unroll
  for (int r = 0; r < 16; r++) linv[r] = 1.0f / caccl[r];

  // epilogue: scalar scatter into the 16x16 FRAGMENT-MAJOR ctxf for gemm_o
#pragma unroll
  for (int dt = 0; dt < 2; dt++) {
    const int c = colbase + dt * 32 + l31;  // global feature col 0..511
    const long ckb = (long)(c >> 6);
    const int cbit = (c >> 5) & 1;
    const int lane16 = ((c >> 3) & 3) * 16;
    const int e = c & 7;
#pragma unroll
    for (int r = 0; r < 16; r++) {
      long row = qrow0 + (r & 3) + 8 * (r >> 2) + 4 * hi;
      long off = ((((row >> 7) * 8 + ckb) * 16 + ((row >> 4) & 7) * 2 + cbit) * 64 +
                  lane16 + (row & 15)) * 8 + e;
      ctxf[off] = f2bf(cacc[dt][r] * linv[r]);
    }
  }
}

extern "C" void kernel_launch(void* const* d_in, const int* in_sizes, int n_in,
                              void* d_out, int out_size, void* d_ws, size_t ws_size,
                              hipStream_t stream) {
  (void)in_sizes; (void)n_in; (void)out_size; (void)ws_size;
  const float* x = (const float*)d_in[0];
  const float* Wq = (const float*)d_in[1];
  const float* bq = (const float*)d_in[2];
  const float* Wkv = (const float*)d_in[3];
  const float* bkv = (const float*)d_in[4];
  const float* Wo = (const float*)d_in[5];
  const float* bo = (const float*)d_in[6];

  char* ws = (char*)d_ws;
  unsigned short* Qn_bf = (unsigned short*)(ws);             // 16 MiB
  unsigned short* Kf    = (unsigned short*)(ws + 16777216);  // 16 MiB
  unsigned short* Vf    = (unsigned short*)(ws + 33554432);  // 16 MiB
  unsigned short* ctxf  = (unsigned short*)(ws + 50331648);  // 16 MiB

  gemm_qkv<<<dim3(128, 8), 256, 0, stream>>>(x, Wq, Wkv, bq, bkv, Qn_bf, Kf, Vf);

  attn_cos<<<512, 512, 0, stream>>>(Qn_bf, Kf, Vf, ctxf);

  gemm_o<<<dim3(128, 4), 256, 0, stream>>>(ctxf, Wo, bo, (float*)d_out);
}

// Round 9
// 228.513 us; speedup vs baseline: 1.1951x; 1.1690x over previous
//
#include <hip/hip_runtime.h>

typedef __attribute__((ext_vector_type(8))) short bf16x8;
typedef __attribute__((ext_vector_type(8))) _Float16 f16x8;
typedef __attribute__((ext_vector_type(2))) _Float16 f16x2;
typedef __attribute__((ext_vector_type(4))) float f32x4;
typedef __attribute__((ext_vector_type(16))) float f32x16;
typedef __attribute__((ext_vector_type(2))) unsigned int u32x2;

__device__ __forceinline__ unsigned short f2bf(float f) {
  union { float f; unsigned int i; } v;
  v.f = f;
  unsigned int r = v.i + 0x7FFFu + ((v.i >> 16) & 1u);  // RNE
  return (unsigned short)(r >> 16);
}

__device__ __forceinline__ f16x2 cvt_pk(float a, float b) {
  return __builtin_bit_cast(f16x2, __builtin_amdgcn_cvt_pkrtz(a, b));
}

__device__ __forceinline__ unsigned as_u32(f16x2 x) {
  return __builtin_bit_cast(unsigned int, x);
}
__device__ __forceinline__ f16x2 as_f16x2(unsigned x) {
  return __builtin_bit_cast(f16x2, x);
}

// permlane32_swap: ret.x[l<32]=a[l], ret.x[l>=32]=b[l-32];
//                  ret.y[l<32]=a[l+32], ret.y[l>=32]=b[l].
#if __has_builtin(__builtin_amdgcn_permlane32_swap)
__device__ __forceinline__ u32x2 plswap(unsigned a, unsigned b) {
  return __builtin_amdgcn_permlane32_swap(a, b, false, false);
}
#else
__device__ __forceinline__ u32x2 plswap(unsigned a, unsigned b) {
  unsigned pa = (unsigned)__shfl_xor((int)a, 32);
  unsigned pb = (unsigned)__shfl_xor((int)b, 32);
  int hi = (int)(threadIdx.x & 32);
  u32x2 r;
  r.x = hi ? pb : a;
  r.y = hi ? b : pa;
  return r;
}
#endif

__device__ __forceinline__ f16x8 pack4(f16x2 a, f16x2 b, f16x2 c, f16x2 d) {
  union { f16x2 h[4]; f16x8 v; } u;
  u.h[0] = a; u.h[1] = b; u.h[2] = c; u.h[3] = d;
  return u.v;
}

// async global->LDS, 16B/lane. LDS dst = wave-uniform base + lane*16.
__device__ __forceinline__ void gl_lds16(const unsigned short* g, unsigned short* l) {
  __builtin_amdgcn_global_load_lds(
      (const __attribute__((address_space(1))) unsigned int*)g,
      (__attribute__((address_space(3))) unsigned int*)l, 16, 0, 0);
}

// e^x on [-1,1], Chebyshev-truncated degree 5 (abs err ~5e-5), packed f16.
__device__ __forceinline__ f16x2 exp_poly(f16x2 x) {
  const f16x2 a5 = {(_Float16)0.00868682f, (_Float16)0.00868682f};
  const f16x2 a4 = {(_Float16)0.04379392f, (_Float16)0.04379392f};
  const f16x2 a3 = {(_Float16)0.16648887f, (_Float16)0.16648887f};
  const f16x2 a2 = {(_Float16)0.49919676f, (_Float16)0.49919676f};
  const f16x2 a1 = {(_Float16)1.00002229f, (_Float16)1.00002229f};
  const f16x2 a0 = {(_Float16)1.00004478f, (_Float16)1.00004478f};
#if __has_builtin(__builtin_elementwise_fma)
  f16x2 r = a5;
  r = __builtin_elementwise_fma(r, x, a4);
  r = __builtin_elementwise_fma(r, x, a3);
  r = __builtin_elementwise_fma(r, x, a2);
  r = __builtin_elementwise_fma(r, x, a1);
  r = __builtin_elementwise_fma(r, x, a0);
#else
  f16x2 r = a5;
  r = r * x + a4;
  r = r * x + a3;
  r = r * x + a2;
  r = r * x + a1;
  r = r * x + a0;
#endif
  return r;
}

// ---------------- fp32 -> bf16 convert to FRAGMENT-MAJOR layout ----------------
// Layout: [rtile(=row>>7)][kb(=c>>6)][slot(=((row>>4)&7)*2+((c>>5)&1))]
//         [lane(=((c>>3)&3)*16+(row&15))][e(=c&7)]   (shorts)
__global__ __launch_bounds__(256) void cvt_all(
    const float* __restrict__ x, const float* __restrict__ wq,
    const float* __restrict__ wkv, const float* __restrict__ wo,
    unsigned short* __restrict__ xf, unsigned short* __restrict__ wqf,
    unsigned short* __restrict__ wkvf, unsigned short* __restrict__ wof) {
  int b = blockIdx.x;
  const float* in;
  unsigned short* out;
  int i;
  if (b < 8192) { in = x; out = xf; i = b * 256 + threadIdx.x; }
  else if (b < 8448) { in = wq; out = wqf; i = (b - 8192) * 256 + threadIdx.x; }
  else if (b < 8704) { in = wkv; out = wkvf; i = (b - 8448) * 256 + threadIdx.x; }
  else { in = wo; out = wof; i = (b - 8704) * 256 + threadIdx.x; }
  float4 v = ((const float4*)in)[i];
  int f = i << 2;
  int row = f >> 9, c = f & 511;
  long off = ((((long)(row >> 7) * 8 + (c >> 6)) * 16 + ((row >> 4) & 7) * 2 +
               ((c >> 5) & 1)) * 64 + ((c >> 3) & 3) * 16 + (row & 15)) * 8 + (c & 7);
  ushort4 o;
  o.x = f2bf(v.x);
  o.y = f2bf(v.y);
  o.z = f2bf(v.z);
  o.w = f2bf(v.w);
  *(ushort4*)(out + off) = o;
}

// ---------------- fused Q + KV projection GEMM (fragment-major in) ----------------
// Main loop = r4 structure (bf16 frag-major inputs, gl_lds16 staging).
// NEW epilogue: all outputs routed through LDS (reusing the 32KB stage buffer)
// so every global store is a coalesced dwordx4 (1KB/wave/inst) instead of
// scattered 2B scalars. Output bytes identical to round-8 formulas:
//   Qn: bf16 row-major, normalized.
//   Kf: 32x32 A-frag: slot=(k>>5)*4+(d>>4); lane=(k&31)|(((d>>3)&1)<<5); e=d&7
//   Vf: 32x32 B-frag: slot=(d>>5)*4+(k>>4); lane=(d&31)|(((k>>3)&1)<<5); e=k&7
__global__ __launch_bounds__(256) void gemm_qkv(
    const unsigned short* __restrict__ xf, const unsigned short* __restrict__ Wqf,
    const unsigned short* __restrict__ Wkvf, const float* __restrict__ bq,
    const float* __restrict__ bkv, unsigned short* __restrict__ Qn,
    unsigned short* __restrict__ Kf, unsigned short* __restrict__ Vf) {
  __shared__ __attribute__((aligned(16))) unsigned short smem[16384];  // 32 KB
  unsigned short* lA = smem;
  unsigned short* lB = smem + 8192;
  const int isKV = (int)(blockIdx.y >> 2);
  const unsigned short* Btf = isKV ? Wkvf : Wqf;
  const float* bias = isKV ? bkv : bq;
  const int tid = threadIdx.x;
  const int lane = tid & 63;
  const int quad = lane >> 4, m16 = lane & 15;
  const int w = tid >> 6;
  const int wm = w >> 1, wn = w & 1;
  const long mb = (long)blockIdx.x * 128;
  const int nt = (int)(blockIdx.y & 3);
  const long nb = (long)nt * 128;
  f32x4 acc[4][4];
#pragma unroll
  for (int i = 0; i < 4; i++)
#pragma unroll
    for (int j = 0; j < 4; j++) acc[i][j] = (f32x4){0.f, 0.f, 0.f, 0.f};

  for (int kb = 0; kb < 8; kb++) {
    __syncthreads();
    {
      const unsigned short* gA =
          xf + (((long)blockIdx.x * 8 + kb) * 16 + 4 * w) * 512 + lane * 8;
      gl_lds16(gA, &lA[(4 * w + 0) * 512]);
      gl_lds16(gA + 512, &lA[(4 * w + 1) * 512]);
      gl_lds16(gA + 1024, &lA[(4 * w + 2) * 512]);
      gl_lds16(gA + 1536, &lA[(4 * w + 3) * 512]);
      const unsigned short* gB =
          Btf + (((long)nt * 8 + kb) * 16 + 4 * w) * 512 + lane * 8;
      gl_lds16(gB, &lB[(4 * w + 0) * 512]);
      gl_lds16(gB + 512, &lB[(4 * w + 1) * 512]);
      gl_lds16(gB + 1024, &lB[(4 * w + 2) * 512]);
      gl_lds16(gB + 1536, &lB[(4 * w + 3) * 512]);
    }
    __syncthreads();
#pragma unroll
    for (int ks = 0; ks < 2; ks++) {
      bf16x8 af[4], bfr[4];
#pragma unroll
      for (int i = 0; i < 4; i++)
        af[i] = *(const bf16x8*)&lA[(((wm * 4 + i) << 1) | ks) * 512 + lane * 8];
#pragma unroll
      for (int j = 0; j < 4; j++)
        bfr[j] = *(const bf16x8*)&lB[(((wn * 4 + j) << 1) | ks) * 512 + lane * 8];
#pragma unroll
      for (int i = 0; i < 4; i++)
#pragma unroll
        for (int j = 0; j < 4; j++)
          acc[i][j] =
              __builtin_amdgcn_mfma_f32_16x16x32_bf16(af[i], bfr[j], acc[i][j], 0, 0, 0);
    }
  }

  // ---------------- LDS-coalesced epilogue ----------------
  float bb[4], inv_s[4][4];
#pragma unroll
  for (int j = 0; j < 4; j++) bb[j] = bias[nb + wn * 64 + j * 16 + m16];
  __syncthreads();  // all MFMA LDS reads done before smem reuse

  if (!isKV) {
    // Q: normalized bf16 into smem[row*128+col] (128x128 tile = 32 KB)
#pragma unroll
    for (int i = 0; i < 4; i++) {
      float val[4][4];
#pragma unroll
      for (int j = 0; j < 4; j++)
#pragma unroll
        for (int r = 0; r < 4; r++) val[j][r] = acc[i][j][r] + bb[j];
#pragma unroll
      for (int r = 0; r < 4; r++) {
        float s = val[0][r] * val[0][r] + val[1][r] * val[1][r] +
                  val[2][r] * val[2][r] + val[3][r] * val[3][r];
        s += __shfl_xor(s, 1);
        s += __shfl_xor(s, 2);
        s += __shfl_xor(s, 4);
        s += __shfl_xor(s, 8);
        float inv = 1.0f / fmaxf(sqrtf(s), 1e-12f);
#pragma unroll
        for (int j = 0; j < 4; j++)
          smem[(wm * 64 + i * 16 + quad * 4 + r) * 128 + wn * 64 + j * 16 + m16] =
              f2bf(val[j][r] * inv);
      }
    }
    __syncthreads();
    // coalesced out-copy: wave w -> rows w*32..w*32+31 (256B contiguous per row)
#pragma unroll
    for (int it = 0; it < 8; it++) {
      int row = w * 32 + it * 4 + (lane >> 4);
      uint4 d = *(const uint4*)&smem[row * 128 + (lane & 15) * 8];
      *(uint4*)&Qn[(mb + row) * 512 + nb + (lane & 15) * 8] = d;
    }
  } else {
    // ---- K phase: normalized bf16, fragment order, region (wn*2+wm)*4096 ----
#pragma unroll
    for (int i = 0; i < 4; i++) {
      float val[4][4];
#pragma unroll
      for (int j = 0; j < 4; j++)
#pragma unroll
        for (int r = 0; r < 4; r++) val[j][r] = acc[i][j][r] + bb[j];
#pragma unroll
      for (int r = 0; r < 4; r++) {
        float s = val[0][r] * val[0][r] + val[1][r] * val[1][r] +
                  val[2][r] * val[2][r] + val[3][r] * val[3][r];
        s += __shfl_xor(s, 1);
        s += __shfl_xor(s, 2);
        s += __shfl_xor(s, 4);
        s += __shfl_xor(s, 8);
        inv_s[i][r] = 1.0f / fmaxf(sqrtf(s), 1e-12f);
      }
      const int rb = (wn * 2 + wm) * 4096;
#pragma unroll
      for (int j = 0; j < 4; j++) {
        const int slot = (i >> 1) * 4 + j;
#pragma unroll
        for (int r = 0; r < 4; r++) {
          const int lf = (((i & 1) * 16 + quad * 4 + r) | ((m16 >> 3) << 5));
          smem[rb + slot * 512 + lf * 8 + (m16 & 7)] = f2bf(val[j][r] * inv_s[i][r]);
        }
      }
    }
    __syncthreads();
    // K out-copy: wave w -> head h0+(w&1), tile (w>>1); 8KB fully coalesced
    {
      const int hh = (int)(nb >> 6) + (w & 1);
      const int gq = (int)(mb >> 11) * 8 + hh;
      const int kt0 = (((int)(mb & 2047)) >> 6) + (w >> 1);
      const long gb = ((long)gq * 32 + kt0) * 4096;
      const int rb = ((w & 1) * 2 + (w >> 1)) * 4096;
#pragma unroll
      for (int it = 0; it < 8; it++) {
        uint4 d = *(const uint4*)&smem[rb + it * 512 + lane * 8];
        *(uint4*)&Kf[gb + it * 512 + lane * 8] = d;
      }
    }
    __syncthreads();
    // ---- V phase: unnormalized f16, fragment order (recompute from live acc) ----
    {
      const int rb = (wn * 2 + wm) * 4096;
#pragma unroll
      for (int i = 0; i < 4; i++)
#pragma unroll
        for (int j = 0; j < 4; j++) {
          f16x2 lo = cvt_pk(acc[i][j][0] + bb[j], acc[i][j][1] + bb[j]);
          f16x2 hi2 = cvt_pk(acc[i][j][2] + bb[j], acc[i][j][3] + bb[j]);
          const int slot = (j >> 1) * 4 + i;
          const int lf = (((j & 1) * 16 + m16) | ((quad >> 1) << 5));
          *(uint2*)&smem[rb + slot * 512 + lf * 8 + (quad & 1) * 4] =
              make_uint2(as_u32(lo), as_u32(hi2));
        }
    }
    __syncthreads();
    // V out-copy
    {
      const int hh = (int)(nb >> 6) + (w & 1);
      const int gq = (int)(mb >> 11) * 8 + hh;
      const int kt0 = (((int)(mb & 2047)) >> 6) + (w >> 1);
      const long gb = ((long)gq * 32 + kt0) * 4096;
      const int rb = ((w & 1) * 2 + (w >> 1)) * 4096;
#pragma unroll
      for (int it = 0; it < 8; it++) {
        uint4 d = *(const uint4*)&smem[rb + it * 512 + lane * 8];
        *(uint4*)&Vf[gb + it * 512 + lane * 8] = d;
      }
    }
  }
}

// ---------------- output projection GEMM (fragment-major in, f32 out) ----------------
__global__ __launch_bounds__(256) void gemm_o(
    const unsigned short* __restrict__ Af, const unsigned short* __restrict__ Btf,
    const float* __restrict__ bias, float* __restrict__ Cout) {
  __shared__ __attribute__((aligned(16))) unsigned short lA[16 * 512];
  __shared__ __attribute__((aligned(16))) unsigned short lB[16 * 512];
  const int tid = threadIdx.x;
  const int lane = tid & 63;
  const int quad = lane >> 4, m16 = lane & 15;
  const int w = tid >> 6;
  const int wm = w >> 1, wn = w & 1;
  const long mb = (long)blockIdx.x * 128;
  const int nt = (int)blockIdx.y;
  const long nb = (long)nt * 128;
  f32x4 acc[4][4];
#pragma unroll
  for (int i = 0; i < 4; i++)
#pragma unroll
    for (int j = 0; j < 4; j++) acc[i][j] = (f32x4){0.f, 0.f, 0.f, 0.f};

  for (int kb = 0; kb < 8; kb++) {
    __syncthreads();
    {
      const unsigned short* gA =
          Af + (((long)blockIdx.x * 8 + kb) * 16 + 4 * w) * 512 + lane * 8;
      gl_lds16(gA, &lA[(4 * w + 0) * 512]);
      gl_lds16(gA + 512, &lA[(4 * w + 1) * 512]);
      gl_lds16(gA + 1024, &lA[(4 * w + 2) * 512]);
      gl_lds16(gA + 1536, &lA[(4 * w + 3) * 512]);
      const unsigned short* gB =
          Btf + (((long)nt * 8 + kb) * 16 + 4 * w) * 512 + lane * 8;
      gl_lds16(gB, &lB[(4 * w + 0) * 512]);
      gl_lds16(gB + 512, &lB[(4 * w + 1) * 512]);
      gl_lds16(gB + 1024, &lB[(4 * w + 2) * 512]);
      gl_lds16(gB + 1536, &lB[(4 * w + 3) * 512]);
    }
    __syncthreads();
#pragma unroll
    for (int ks = 0; ks < 2; ks++) {
      bf16x8 af[4], bfr[4];
#pragma unroll
      for (int i = 0; i < 4; i++)
        af[i] = *(const bf16x8*)&lA[(((wm * 4 + i) << 1) | ks) * 512 + lane * 8];
#pragma unroll
      for (int j = 0; j < 4; j++)
        bfr[j] = *(const bf16x8*)&lB[(((wn * 4 + j) << 1) | ks) * 512 + lane * 8];
#pragma unroll
      for (int i = 0; i < 4; i++)
#pragma unroll
        for (int j = 0; j < 4; j++)
          acc[i][j] =
              __builtin_amdgcn_mfma_f32_16x16x32_bf16(af[i], bfr[j], acc[i][j], 0, 0, 0);
    }
  }
#pragma unroll
  for (int i = 0; i < 4; i++) {
    long row0 = mb + wm * 64 + i * 16 + quad * 4;
#pragma unroll
    for (int j = 0; j < 4; j++) {
      long col = nb + wn * 64 + j * 16 + m16;
      float bb = bias[col];
#pragma unroll
      for (int r = 0; r < 4; r++) Cout[(row0 + r) * 512 + col] = acc[i][j][r] + bb;
    }
  }
}

// ---------------- cosine attention (r8 version: best known, 87.6us) ----------------
// Triple-buffered gl_lds staging, counted vmcnt(2) + raw barrier, setprio on
// MFMA clusters, 32x32 MFMA, in-register P via permlane32_swap, zero-C first
// QK MFMA, li via ones-MFMA (rows align with cacc -> no epilogue shuffles).
__global__ __launch_bounds__(512, 4) void attn_cos(
    const unsigned short* __restrict__ Qn, const unsigned short* __restrict__ Kf,
    const unsigned short* __restrict__ Vf, unsigned short* __restrict__ ctxf) {
  __shared__ __attribute__((aligned(16))) unsigned short lK[3][8 * 512];   // 24 KB
  __shared__ __attribute__((aligned(16))) unsigned short lVt[3][8 * 512];  // 24 KB
  const int id = (int)blockIdx.x;
  const int g = ((id >> 6) << 3) | (id & 7);  // 0..63
  const int qt = (id >> 3) & 7;               // 0..7 (256-row tiles)
  const int bm = g >> 3, h = g & 7;
  const int tid = threadIdx.x;
  const int lane = tid & 63;
  const int l31 = lane & 31, hi = lane >> 5;
  const int w = tid >> 6;  // 0..7
  const long qrow0 = (long)bm * 2048 + qt * 256 + w * 32;
  const int colbase = h * 64;

  // Q B-fragments (32x32x16): col=q=l31, k-elem = d = dd*16 + hi*8 + e
  bf16x8 qf[4];
#pragma unroll
  for (int dd = 0; dd < 4; dd++)
    qf[dd] = *(const bf16x8*)(Qn + (qrow0 + l31) * 512 + colbase + dd * 16 + hi * 8);

  f32x16 cacc[2];
  f32x16 caccl;  // li via ones-MFMA: rows align exactly with cacc rows
#pragma unroll
  for (int e = 0; e < 16; e++) { cacc[0][e] = 0.f; cacc[1][e] = 0.f; caccl[e] = 0.f; }
  const f16x8 onesv = {(_Float16)1.0f, (_Float16)1.0f, (_Float16)1.0f, (_Float16)1.0f,
                       (_Float16)1.0f, (_Float16)1.0f, (_Float16)1.0f, (_Float16)1.0f};
  const f32x16 zv = {};  // zero-C for the first QK MFMA

#define STAGE(buf, ktn)                                                  \
  {                                                                      \
    const long tb_ = ((long)g * 32 + (ktn)) * 8;                         \
    gl_lds16(Kf + (tb_ + w) * 512 + lane * 8, &lK[(buf)][w * 512]);      \
    gl_lds16(Vf + (tb_ + w) * 512 + lane * 8, &lVt[(buf)][w * 512]);     \
  }

  // prologue: 2-deep prefetch. After vmcnt(2), buf0 landed (buf1 may be in flight).
  STAGE(0, 0);
  STAGE(1, 1);
  asm volatile("s_waitcnt vmcnt(2)" ::: "memory");
  __builtin_amdgcn_s_barrier();
  __builtin_amdgcn_sched_barrier(0);

  int cur = 0, nxt = 2;
  for (int kt = 0; kt < 32; ++kt) {
    STAGE(nxt, (kt + 2) & 31);
    __builtin_amdgcn_sched_barrier(0);
    const unsigned short* bK = lK[cur];
    const unsigned short* bV = lVt[cur];

    // ---- QK^T (32x32x16), zero-C first MFMA: no per-kt acc init ----
    f32x16 sacc[2];
    __builtin_amdgcn_s_setprio(1);
    {
      bf16x8 k0 = *(const bf16x8*)&bK[(0 * 4 + 0) * 512 + lane * 8];
      bf16x8 k1 = *(const bf16x8*)&bK[(1 * 4 + 0) * 512 + lane * 8];
      sacc[0] = __builtin_amdgcn_mfma_f32_32x32x16_bf16(k0, qf[0], zv, 0, 0, 0);
      sacc[1] = __builtin_amdgcn_mfma_f32_32x32x16_bf16(k1, qf[0], zv, 0, 0, 0);
    }
#pragma unroll
    for (int dd = 1; dd < 4; dd++) {
      bf16x8 k0 = *(const bf16x8*)&bK[(0 * 4 + dd) * 512 + lane * 8];
      bf16x8 k1 = *(const bf16x8*)&bK[(1 * 4 + dd) * 512 + lane * 8];
      sacc[0] = __builtin_amdgcn_mfma_f32_32x32x16_bf16(k0, qf[dd], sacc[0], 0, 0, 0);
      sacc[1] = __builtin_amdgcn_mfma_f32_32x32x16_bf16(k1, qf[dd], sacc[1], 0, 0, 0);
    }
    __builtin_amdgcn_s_setprio(0);

    // ---- exp (packed f16); k(reg) = (reg&3)+8*(reg>>2)+4*hi ----
    f16x2 pe[2][8];
#pragma unroll
    for (int kk = 0; kk < 2; kk++)
#pragma unroll
      for (int t = 0; t < 8; t++)
        pe[kk][t] = exp_poly(cvt_pk(sacc[kk][2 * t], sacc[kk][2 * t + 1]));

    // ---- PA via permlane32_swap + PV + ones-li (32x32x16 f16) ----
    __builtin_amdgcn_s_setprio(1);
#pragma unroll
    for (int kk = 0; kk < 2; kk++)
#pragma unroll
      for (int s = 0; s < 2; s++) {
        u32x2 r0 = plswap(as_u32(pe[kk][4 * s + 0]), as_u32(pe[kk][4 * s + 2]));
        u32x2 r1 = plswap(as_u32(pe[kk][4 * s + 1]), as_u32(pe[kk][4 * s + 3]));
        f16x8 pa = pack4(as_f16x2(r0.x), as_f16x2(r1.x), as_f16x2(r0.y), as_f16x2(r1.y));
        const int ksub = kk * 2 + s;
        f16x8 v0 = *(const f16x8*)&bV[(0 * 4 + ksub) * 512 + lane * 8];
        f16x8 v1 = *(const f16x8*)&bV[(1 * 4 + ksub) * 512 + lane * 8];
        cacc[0] = __builtin_amdgcn_mfma_f32_32x32x16_f16(pa, v0, cacc[0], 0, 0, 0);
        cacc[1] = __builtin_amdgcn_mfma_f32_32x32x16_f16(pa, v1, cacc[1], 0, 0, 0);
        caccl = __builtin_amdgcn_mfma_f32_32x32x16_f16(pa, onesv, caccl, 0, 0, 0);
      }
    __builtin_amdgcn_s_setprio(0);

    // counted wait + RAW barrier: kt+1's stage landed, kt+2's stays in flight.
    asm volatile("s_waitcnt vmcnt(2) lgkmcnt(0)" ::: "memory");
    __builtin_amdgcn_sched_barrier(0);
    __builtin_amdgcn_s_barrier();
    __builtin_amdgcn_sched_barrier(0);
    cur = (cur == 2) ? 0 : cur + 1;
    nxt = (nxt == 2) ? 0 : nxt + 1;
  }
#undef STAGE

  // li: caccl rows == cacc rows -> no shuffles at all
  float linv[16];
#pragma unroll
  for (int r = 0; r < 16; r++) linv[r] = 1.0f / caccl[r];

  // epilogue: scalar scatter into the 16x16 FRAGMENT-MAJOR ctxf for gemm_o
#pragma unroll
  for (int dt = 0; dt < 2; dt++) {
    const int c = colbase + dt * 32 + l31;  // global feature col 0..511
    const long ckb = (long)(c >> 6);
    const int cbit = (c >> 5) & 1;
    const int lane16 = ((c >> 3) & 3) * 16;
    const int e = c & 7;
#pragma unroll
    for (int r = 0; r < 16; r++) {
      long row = qrow0 + (r & 3) + 8 * (r >> 2) + 4 * hi;
      long off = ((((row >> 7) * 8 + ckb) * 16 + ((row >> 4) & 7) * 2 + cbit) * 64 +
                  lane16 + (row & 15)) * 8 + e;
      ctxf[off] = f2bf(cacc[dt][r] * linv[r]);
    }
  }
}

extern "C" void kernel_launch(void* const* d_in, const int* in_sizes, int n_in,
                              void* d_out, int out_size, void* d_ws, size_t ws_size,
                              hipStream_t stream) {
  (void)in_sizes; (void)n_in; (void)out_size; (void)ws_size;
  const float* x = (const float*)d_in[0];
  const float* Wq = (const float*)d_in[1];
  const float* bq = (const float*)d_in[2];
  const float* Wkv = (const float*)d_in[3];
  const float* bkv = (const float*)d_in[4];
  const float* Wo = (const float*)d_in[5];
  const float* bo = (const float*)d_in[6];

  char* ws = (char*)d_ws;
  unsigned short* xf     = (unsigned short*)(ws);             // 16 MiB (reused as ctxf)
  unsigned short* Wqf    = (unsigned short*)(ws + 16777216);  // 512 KiB
  unsigned short* Wkvf   = (unsigned short*)(ws + 17301504);  // 512 KiB
  unsigned short* Wof    = (unsigned short*)(ws + 17825792);  // 512 KiB
  unsigned short* Qn_bf  = (unsigned short*)(ws + 18350080);  // 16 MiB
  unsigned short* Kf     = (unsigned short*)(ws + 35127296);  // 16 MiB
  unsigned short* Vf     = (unsigned short*)(ws + 51904512);  // 16 MiB
  unsigned short* ctxf   = xf;  // x dead after gemm_qkv

  cvt_all<<<8960, 256, 0, stream>>>(x, Wq, Wkv, Wo, xf, Wqf, Wkvf, Wof);

  gemm_qkv<<<dim3(128, 8), 256, 0, stream>>>(xf, Wqf, Wkvf, bq, bkv, Qn_bf, Kf, Vf);

  attn_cos<<<512, 512, 0, stream>>>(Qn_bf, Kf, Vf, ctxf);

  gemm_o<<<dim3(128, 4), 256, 0, stream>>>(ctxf, Wof, bo, (float*)d_out);
}

// Round 10
// 223.770 us; speedup vs baseline: 1.2204x; 1.0212x over previous
//
#include <hip/hip_runtime.h>

typedef __attribute__((ext_vector_type(8))) short bf16x8;
typedef __attribute__((ext_vector_type(8))) _Float16 f16x8;
typedef __attribute__((ext_vector_type(2))) _Float16 f16x2;
typedef __attribute__((ext_vector_type(4))) float f32x4;
typedef __attribute__((ext_vector_type(16))) float f32x16;
typedef __attribute__((ext_vector_type(2))) unsigned int u32x2;

__device__ __forceinline__ unsigned short f2bf(float f) {
  union { float f; unsigned int i; } v;
  v.f = f;
  unsigned int r = v.i + 0x7FFFu + ((v.i >> 16) & 1u);  // RNE
  return (unsigned short)(r >> 16);
}

__device__ __forceinline__ f16x2 cvt_pk(float a, float b) {
  return __builtin_bit_cast(f16x2, __builtin_amdgcn_cvt_pkrtz(a, b));
}

__device__ __forceinline__ unsigned as_u32(f16x2 x) {
  return __builtin_bit_cast(unsigned int, x);
}
__device__ __forceinline__ f16x2 as_f16x2(unsigned x) {
  return __builtin_bit_cast(f16x2, x);
}

// permlane32_swap: ret.x[l<32]=a[l], ret.x[l>=32]=b[l-32];
//                  ret.y[l<32]=a[l+32], ret.y[l>=32]=b[l].
#if __has_builtin(__builtin_amdgcn_permlane32_swap)
__device__ __forceinline__ u32x2 plswap(unsigned a, unsigned b) {
  return __builtin_amdgcn_permlane32_swap(a, b, false, false);
}
#else
__device__ __forceinline__ u32x2 plswap(unsigned a, unsigned b) {
  unsigned pa = (unsigned)__shfl_xor((int)a, 32);
  unsigned pb = (unsigned)__shfl_xor((int)b, 32);
  int hi = (int)(threadIdx.x & 32);
  u32x2 r;
  r.x = hi ? pb : a;
  r.y = hi ? b : pa;
  return r;
}
#endif

__device__ __forceinline__ f16x8 pack4(f16x2 a, f16x2 b, f16x2 c, f16x2 d) {
  union { f16x2 h[4]; f16x8 v; } u;
  u.h[0] = a; u.h[1] = b; u.h[2] = c; u.h[3] = d;
  return u.v;
}

// async global->LDS, 16B/lane. LDS dst = wave-uniform base + lane*16.
__device__ __forceinline__ void gl_lds16(const unsigned short* g, unsigned short* l) {
  __builtin_amdgcn_global_load_lds(
      (const __attribute__((address_space(1))) unsigned int*)g,
      (__attribute__((address_space(3))) unsigned int*)l, 16, 0, 0);
}

// e^x on [-1,1], Chebyshev-truncated degree 5 (abs err ~5e-5), packed f16.
__device__ __forceinline__ f16x2 exp_poly(f16x2 x) {
  const f16x2 a5 = {(_Float16)0.00868682f, (_Float16)0.00868682f};
  const f16x2 a4 = {(_Float16)0.04379392f, (_Float16)0.04379392f};
  const f16x2 a3 = {(_Float16)0.16648887f, (_Float16)0.16648887f};
  const f16x2 a2 = {(_Float16)0.49919676f, (_Float16)0.49919676f};
  const f16x2 a1 = {(_Float16)1.00002229f, (_Float16)1.00002229f};
  const f16x2 a0 = {(_Float16)1.00004478f, (_Float16)1.00004478f};
#if __has_builtin(__builtin_elementwise_fma)
  f16x2 r = a5;
  r = __builtin_elementwise_fma(r, x, a4);
  r = __builtin_elementwise_fma(r, x, a3);
  r = __builtin_elementwise_fma(r, x, a2);
  r = __builtin_elementwise_fma(r, x, a1);
  r = __builtin_elementwise_fma(r, x, a0);
#else
  f16x2 r = a5;
  r = r * x + a4;
  r = r * x + a3;
  r = r * x + a2;
  r = r * x + a1;
  r = r * x + a0;
#endif
  return r;
}

// ---------------- fp32 -> bf16 convert to FRAGMENT-MAJOR layout ----------------
// Layout: [rtile(=row>>7)][kb(=c>>6)][slot(=((row>>4)&7)*2+((c>>5)&1))]
//         [lane(=((c>>3)&3)*16+(row&15))][e(=c&7)]   (shorts)
__global__ __launch_bounds__(256) void cvt_all(
    const float* __restrict__ x, const float* __restrict__ wq,
    const float* __restrict__ wkv, const float* __restrict__ wo,
    unsigned short* __restrict__ xf, unsigned short* __restrict__ wqf,
    unsigned short* __restrict__ wkvf, unsigned short* __restrict__ wof) {
  int b = blockIdx.x;
  const float* in;
  unsigned short* out;
  int i;
  if (b < 8192) { in = x; out = xf; i = b * 256 + threadIdx.x; }
  else if (b < 8448) { in = wq; out = wqf; i = (b - 8192) * 256 + threadIdx.x; }
  else if (b < 8704) { in = wkv; out = wkvf; i = (b - 8448) * 256 + threadIdx.x; }
  else { in = wo; out = wof; i = (b - 8704) * 256 + threadIdx.x; }
  float4 v = ((const float4*)in)[i];
  int f = i << 2;
  int row = f >> 9, c = f & 511;
  long off = ((((long)(row >> 7) * 8 + (c >> 6)) * 16 + ((row >> 4) & 7) * 2 +
               ((c >> 5) & 1)) * 64 + ((c >> 3) & 3) * 16 + (row & 15)) * 8 + (c & 7);
  ushort4 o;
  o.x = f2bf(v.x);
  o.y = f2bf(v.y);
  o.z = f2bf(v.z);
  o.w = f2bf(v.w);
  *(ushort4*)(out + off) = o;
}

// ---------------- fused Q + KV projection GEMM (fragment-major in) ----------------
// K-loop now DOUBLE-BUFFERED with early stage issue: per kb, the stage of
// kb+1 is issued into the other buffer BEFORE computing kb, so its L3/HBM
// latency cooks under ~400 cyc of MFMA; the end-of-kb vmcnt(0) drains only
// the residue instead of the full latency (this was the single-buffer
// exposed-drain stall: ~700 cyc x 8 kb per block).
// Outputs byte-identical to round 9 (LDS-coalesced epilogue kept).
__global__ __launch_bounds__(256) void gemm_qkv(
    const unsigned short* __restrict__ xf, const unsigned short* __restrict__ Wqf,
    const unsigned short* __restrict__ Wkvf, const float* __restrict__ bq,
    const float* __restrict__ bkv, unsigned short* __restrict__ Qn,
    unsigned short* __restrict__ Kf, unsigned short* __restrict__ Vf) {
  __shared__ __attribute__((aligned(16))) unsigned short lA[2][8192];  // 32 KB
  __shared__ __attribute__((aligned(16))) unsigned short lB[2][8192];  // 32 KB
  unsigned short* smem = &lA[0][0];  // epilogue staging alias (32 KB)
  const int isKV = (int)(blockIdx.y >> 2);
  const unsigned short* Btf = isKV ? Wkvf : Wqf;
  const float* bias = isKV ? bkv : bq;
  const int tid = threadIdx.x;
  const int lane = tid & 63;
  const int quad = lane >> 4, m16 = lane & 15;
  const int w = tid >> 6;
  const int wm = w >> 1, wn = w & 1;
  const long mb = (long)blockIdx.x * 128;
  const int nt = (int)(blockIdx.y & 3);
  const long nb = (long)nt * 128;
  f32x4 acc[4][4];
#pragma unroll
  for (int i = 0; i < 4; i++)
#pragma unroll
    for (int j = 0; j < 4; j++) acc[i][j] = (f32x4){0.f, 0.f, 0.f, 0.f};

#define QSTAGE(buf, kb)                                                       \
  {                                                                           \
    const unsigned short* gA =                                                \
        xf + (((long)blockIdx.x * 8 + (kb)) * 16 + 4 * w) * 512 + lane * 8;   \
    gl_lds16(gA, &lA[(buf)][(4 * w + 0) * 512]);                              \
    gl_lds16(gA + 512, &lA[(buf)][(4 * w + 1) * 512]);                        \
    gl_lds16(gA + 1024, &lA[(buf)][(4 * w + 2) * 512]);                       \
    gl_lds16(gA + 1536, &lA[(buf)][(4 * w + 3) * 512]);                       \
    const unsigned short* gB =                                                \
        Btf + (((long)nt * 8 + (kb)) * 16 + 4 * w) * 512 + lane * 8;          \
    gl_lds16(gB, &lB[(buf)][(4 * w + 0) * 512]);                              \
    gl_lds16(gB + 512, &lB[(buf)][(4 * w + 1) * 512]);                        \
    gl_lds16(gB + 1024, &lB[(buf)][(4 * w + 2) * 512]);                       \
    gl_lds16(gB + 1536, &lB[(buf)][(4 * w + 3) * 512]);                       \
  }

  QSTAGE(0, 0);
  asm volatile("s_waitcnt vmcnt(0)" ::: "memory");
  __builtin_amdgcn_s_barrier();
  __builtin_amdgcn_sched_barrier(0);

  int cur = 0;
  for (int kb = 0; kb < 8; kb++) {
    if (kb < 7) QSTAGE(cur ^ 1, kb + 1);  // async; lands during compute below
    __builtin_amdgcn_sched_barrier(0);
#pragma unroll
    for (int ks = 0; ks < 2; ks++) {
      bf16x8 af[4], bfr[4];
#pragma unroll
      for (int i = 0; i < 4; i++)
        af[i] = *(const bf16x8*)&lA[cur][(((wm * 4 + i) << 1) | ks) * 512 + lane * 8];
#pragma unroll
      for (int j = 0; j < 4; j++)
        bfr[j] = *(const bf16x8*)&lB[cur][(((wn * 4 + j) << 1) | ks) * 512 + lane * 8];
#pragma unroll
      for (int i = 0; i < 4; i++)
#pragma unroll
        for (int j = 0; j < 4; j++)
          acc[i][j] =
              __builtin_amdgcn_mfma_f32_16x16x32_bf16(af[i], bfr[j], acc[i][j], 0, 0, 0);
    }
    // drain residue of the early-issued stage + my LDS reads, then barrier
    asm volatile("s_waitcnt vmcnt(0) lgkmcnt(0)" ::: "memory");
    __builtin_amdgcn_sched_barrier(0);
    __builtin_amdgcn_s_barrier();
    __builtin_amdgcn_sched_barrier(0);
    cur ^= 1;
  }
#undef QSTAGE

  // ---------------- LDS-coalesced epilogue (round-9, unchanged) ----------------
  float bb[4], inv_s[4][4];
#pragma unroll
  for (int j = 0; j < 4; j++) bb[j] = bias[nb + wn * 64 + j * 16 + m16];
  // last K-loop barrier already ordered all LDS reads before smem reuse

  if (!isKV) {
    // Q: normalized bf16 into smem[row*128+col] (128x128 tile = 32 KB)
#pragma unroll
    for (int i = 0; i < 4; i++) {
      float val[4][4];
#pragma unroll
      for (int j = 0; j < 4; j++)
#pragma unroll
        for (int r = 0; r < 4; r++) val[j][r] = acc[i][j][r] + bb[j];
#pragma unroll
      for (int r = 0; r < 4; r++) {
        float s = val[0][r] * val[0][r] + val[1][r] * val[1][r] +
                  val[2][r] * val[2][r] + val[3][r] * val[3][r];
        s += __shfl_xor(s, 1);
        s += __shfl_xor(s, 2);
        s += __shfl_xor(s, 4);
        s += __shfl_xor(s, 8);
        float inv = 1.0f / fmaxf(sqrtf(s), 1e-12f);
#pragma unroll
        for (int j = 0; j < 4; j++)
          smem[(wm * 64 + i * 16 + quad * 4 + r) * 128 + wn * 64 + j * 16 + m16] =
              f2bf(val[j][r] * inv);
      }
    }
    __syncthreads();
    // coalesced out-copy: wave w -> rows w*32..w*32+31 (256B contiguous per row)
#pragma unroll
    for (int it = 0; it < 8; it++) {
      int row = w * 32 + it * 4 + (lane >> 4);
      uint4 d = *(const uint4*)&smem[row * 128 + (lane & 15) * 8];
      *(uint4*)&Qn[(mb + row) * 512 + nb + (lane & 15) * 8] = d;
    }
  } else {
    // ---- K phase: normalized bf16, fragment order, region (wn*2+wm)*4096 ----
#pragma unroll
    for (int i = 0; i < 4; i++) {
      float val[4][4];
#pragma unroll
      for (int j = 0; j < 4; j++)
#pragma unroll
        for (int r = 0; r < 4; r++) val[j][r] = acc[i][j][r] + bb[j];
#pragma unroll
      for (int r = 0; r < 4; r++) {
        float s = val[0][r] * val[0][r] + val[1][r] * val[1][r] +
                  val[2][r] * val[2][r] + val[3][r] * val[3][r];
        s += __shfl_xor(s, 1);
        s += __shfl_xor(s, 2);
        s += __shfl_xor(s, 4);
        s += __shfl_xor(s, 8);
        inv_s[i][r] = 1.0f / fmaxf(sqrtf(s), 1e-12f);
      }
      const int rb = (wn * 2 + wm) * 4096;
#pragma unroll
      for (int j = 0; j < 4; j++) {
        const int slot = (i >> 1) * 4 + j;
#pragma unroll
        for (int r = 0; r < 4; r++) {
          const int lf = (((i & 1) * 16 + quad * 4 + r) | ((m16 >> 3) << 5));
          smem[rb + slot * 512 + lf * 8 + (m16 & 7)] = f2bf(val[j][r] * inv_s[i][r]);
        }
      }
    }
    __syncthreads();
    // K out-copy: wave w -> head h0+(w&1), tile (w>>1); 8KB fully coalesced
    {
      const int hh = (int)(nb >> 6) + (w & 1);
      const int gq = (int)(mb >> 11) * 8 + hh;
      const int kt0 = (((int)(mb & 2047)) >> 6) + (w >> 1);
      const long gb = ((long)gq * 32 + kt0) * 4096;
      const int rb = ((w & 1) * 2 + (w >> 1)) * 4096;
#pragma unroll
      for (int it = 0; it < 8; it++) {
        uint4 d = *(const uint4*)&smem[rb + it * 512 + lane * 8];
        *(uint4*)&Kf[gb + it * 512 + lane * 8] = d;
      }
    }
    __syncthreads();
    // ---- V phase: unnormalized f16, fragment order (recompute from live acc) ----
    {
      const int rb = (wn * 2 + wm) * 4096;
#pragma unroll
      for (int i = 0; i < 4; i++)
#pragma unroll
        for (int j = 0; j < 4; j++) {
          f16x2 lo = cvt_pk(acc[i][j][0] + bb[j], acc[i][j][1] + bb[j]);
          f16x2 hi2 = cvt_pk(acc[i][j][2] + bb[j], acc[i][j][3] + bb[j]);
          const int slot = (j >> 1) * 4 + i;
          const int lf = (((j & 1) * 16 + m16) | ((quad >> 1) << 5));
          *(uint2*)&smem[rb + slot * 512 + lf * 8 + (quad & 1) * 4] =
              make_uint2(as_u32(lo), as_u32(hi2));
        }
    }
    __syncthreads();
    // V out-copy
    {
      const int hh = (int)(nb >> 6) + (w & 1);
      const int gq = (int)(mb >> 11) * 8 + hh;
      const int kt0 = (((int)(mb & 2047)) >> 6) + (w >> 1);
      const long gb = ((long)gq * 32 + kt0) * 4096;
      const int rb = ((w & 1) * 2 + (w >> 1)) * 4096;
#pragma unroll
      for (int it = 0; it < 8; it++) {
        uint4 d = *(const uint4*)&smem[rb + it * 512 + lane * 8];
        *(uint4*)&Vf[gb + it * 512 + lane * 8] = d;
      }
    }
  }
}

// ---------------- output projection GEMM (double-buffered K-loop) ----------------
__global__ __launch_bounds__(256) void gemm_o(
    const unsigned short* __restrict__ Af, const unsigned short* __restrict__ Btf,
    const float* __restrict__ bias, float* __restrict__ Cout) {
  __shared__ __attribute__((aligned(16))) unsigned short lA[2][8192];  // 32 KB
  __shared__ __attribute__((aligned(16))) unsigned short lB[2][8192];  // 32 KB
  const int tid = threadIdx.x;
  const int lane = tid & 63;
  const int quad = lane >> 4, m16 = lane & 15;
  const int w = tid >> 6;
  const int wm = w >> 1, wn = w & 1;
  const long mb = (long)blockIdx.x * 128;
  const int nt = (int)blockIdx.y;
  const long nb = (long)nt * 128;
  f32x4 acc[4][4];
#pragma unroll
  for (int i = 0; i < 4; i++)
#pragma unroll
    for (int j = 0; j < 4; j++) acc[i][j] = (f32x4){0.f, 0.f, 0.f, 0.f};

#define OSTAGE(buf, kb)                                                       \
  {                                                                           \
    const unsigned short* gA =                                                \
        Af + (((long)blockIdx.x * 8 + (kb)) * 16 + 4 * w) * 512 + lane * 8;   \
    gl_lds16(gA, &lA[(buf)][(4 * w + 0) * 512]);                              \
    gl_lds16(gA + 512, &lA[(buf)][(4 * w + 1) * 512]);                        \
    gl_lds16(gA + 1024, &lA[(buf)][(4 * w + 2) * 512]);                       \
    gl_lds16(gA + 1536, &lA[(buf)][(4 * w + 3) * 512]);                       \
    const unsigned short* gB =                                                \
        Btf + (((long)nt * 8 + (kb)) * 16 + 4 * w) * 512 + lane * 8;          \
    gl_lds16(gB, &lB[(buf)][(4 * w + 0) * 512]);                              \
    gl_lds16(gB + 512, &lB[(buf)][(4 * w + 1) * 512]);                        \
    gl_lds16(gB + 1024, &lB[(buf)][(4 * w + 2) * 512]);                       \
    gl_lds16(gB + 1536, &lB[(buf)][(4 * w + 3) * 512]);                       \
  }

  OSTAGE(0, 0);
  asm volatile("s_waitcnt vmcnt(0)" ::: "memory");
  __builtin_amdgcn_s_barrier();
  __builtin_amdgcn_sched_barrier(0);

  int cur = 0;
  for (int kb = 0; kb < 8; kb++) {
    if (kb < 7) OSTAGE(cur ^ 1, kb + 1);
    __builtin_amdgcn_sched_barrier(0);
#pragma unroll
    for (int ks = 0; ks < 2; ks++) {
      bf16x8 af[4], bfr[4];
#pragma unroll
      for (int i = 0; i < 4; i++)
        af[i] = *(const bf16x8*)&lA[cur][(((wm * 4 + i) << 1) | ks) * 512 + lane * 8];
#pragma unroll
      for (int j = 0; j < 4; j++)
        bfr[j] = *(const bf16x8*)&lB[cur][(((wn * 4 + j) << 1) | ks) * 512 + lane * 8];
#pragma unroll
      for (int i = 0; i < 4; i++)
#pragma unroll
        for (int j = 0; j < 4; j++)
          acc[i][j] =
              __builtin_amdgcn_mfma_f32_16x16x32_bf16(af[i], bfr[j], acc[i][j], 0, 0, 0);
    }
    asm volatile("s_waitcnt vmcnt(0) lgkmcnt(0)" ::: "memory");
    __builtin_amdgcn_sched_barrier(0);
    __builtin_amdgcn_s_barrier();
    __builtin_amdgcn_sched_barrier(0);
    cur ^= 1;
  }
#undef OSTAGE

#pragma unroll
  for (int i = 0; i < 4; i++) {
    long row0 = mb + wm * 64 + i * 16 + quad * 4;
#pragma unroll
    for (int j = 0; j < 4; j++) {
      long col = nb + wn * 64 + j * 16 + m16;
      float bb = bias[col];
#pragma unroll
      for (int r = 0; r < 4; r++) Cout[(row0 + r) * 512 + col] = acc[i][j][r] + bb;
    }
  }
}

// ---------------- cosine attention (round-9 version: best known, 86.0us) ----------------
// Triple-buffered gl_lds staging, counted vmcnt(2) + raw barrier, setprio on
// MFMA clusters, 32x32 MFMA, in-register P via permlane32_swap, zero-C first
// QK MFMA, li via ones-MFMA (rows align with cacc -> no epilogue shuffles).
__global__ __launch_bounds__(512, 4) void attn_cos(
    const unsigned short* __restrict__ Qn, const unsigned short* __restrict__ Kf,
    const unsigned short* __restrict__ Vf, unsigned short* __restrict__ ctxf) {
  __shared__ __attribute__((aligned(16))) unsigned short lK[3][8 * 512];   // 24 KB
  __shared__ __attribute__((aligned(16))) unsigned short lVt[3][8 * 512];  // 24 KB
  const int id = (int)blockIdx.x;
  const int g = ((id >> 6) << 3) | (id & 7);  // 0..63
  const int qt = (id >> 3) & 7;               // 0..7 (256-row tiles)
  const int bm = g >> 3, h = g & 7;
  const int tid = threadIdx.x;
  const int lane = tid & 63;
  const int l31 = lane & 31, hi = lane >> 5;
  const int w = tid >> 6;  // 0..7
  const long qrow0 = (long)bm * 2048 + qt * 256 + w * 32;
  const int colbase = h * 64;

  // Q B-fragments (32x32x16): col=q=l31, k-elem = d = dd*16 + hi*8 + e
  bf16x8 qf[4];
#pragma unroll
  for (int dd = 0; dd < 4; dd++)
    qf[dd] = *(const bf16x8*)(Qn + (qrow0 + l31) * 512 + colbase + dd * 16 + hi * 8);

  f32x16 cacc[2];
  f32x16 caccl;  // li via ones-MFMA: rows align exactly with cacc rows
#pragma unroll
  for (int e = 0; e < 16; e++) { cacc[0][e] = 0.f; cacc[1][e] = 0.f; caccl[e] = 0.f; }
  const f16x8 onesv = {(_Float16)1.0f, (_Float16)1.0f, (_Float16)1.0f, (_Float16)1.0f,
                       (_Float16)1.0f, (_Float16)1.0f, (_Float16)1.0f, (_Float16)1.0f};
  const f32x16 zv = {};  // zero-C for the first QK MFMA

#define STAGE(buf, ktn)                                                  \
  {                                                                      \
    const long tb_ = ((long)g * 32 + (ktn)) * 8;                         \
    gl_lds16(Kf + (tb_ + w) * 512 + lane * 8, &lK[(buf)][w * 512]);      \
    gl_lds16(Vf + (tb_ + w) * 512 + lane * 8, &lVt[(buf)][w * 512]);     \
  }

  // prologue: 2-deep prefetch. After vmcnt(2), buf0 landed (buf1 may be in flight).
  STAGE(0, 0);
  STAGE(1, 1);
  asm volatile("s_waitcnt vmcnt(2)" ::: "memory");
  __builtin_amdgcn_s_barrier();
  __builtin_amdgcn_sched_barrier(0);

  int cur = 0, nxt = 2;
  for (int kt = 0; kt < 32; ++kt) {
    STAGE(nxt, (kt + 2) & 31);
    __builtin_amdgcn_sched_barrier(0);
    const unsigned short* bK = lK[cur];
    const unsigned short* bV = lVt[cur];

    // ---- QK^T (32x32x16), zero-C first MFMA: no per-kt acc init ----
    f32x16 sacc[2];
    __builtin_amdgcn_s_setprio(1);
    {
      bf16x8 k0 = *(const bf16x8*)&bK[(0 * 4 + 0) * 512 + lane * 8];
      bf16x8 k1 = *(const bf16x8*)&bK[(1 * 4 + 0) * 512 + lane * 8];
      sacc[0] = __builtin_amdgcn_mfma_f32_32x32x16_bf16(k0, qf[0], zv, 0, 0, 0);
      sacc[1] = __builtin_amdgcn_mfma_f32_32x32x16_bf16(k1, qf[0], zv, 0, 0, 0);
    }
#pragma unroll
    for (int dd = 1; dd < 4; dd++) {
      bf16x8 k0 = *(const bf16x8*)&bK[(0 * 4 + dd) * 512 + lane * 8];
      bf16x8 k1 = *(const bf16x8*)&bK[(1 * 4 + dd) * 512 + lane * 8];
      sacc[0] = __builtin_amdgcn_mfma_f32_32x32x16_bf16(k0, qf[dd], sacc[0], 0, 0, 0);
      sacc[1] = __builtin_amdgcn_mfma_f32_32x32x16_bf16(k1, qf[dd], sacc[1], 0, 0, 0);
    }
    __builtin_amdgcn_s_setprio(0);

    // ---- exp (packed f16); k(reg) = (reg&3)+8*(reg>>2)+4*hi ----
    f16x2 pe[2][8];
#pragma unroll
    for (int kk = 0; kk < 2; kk++)
#pragma unroll
      for (int t = 0; t < 8; t++)
        pe[kk][t] = exp_poly(cvt_pk(sacc[kk][2 * t], sacc[kk][2 * t + 1]));

    // ---- PA via permlane32_swap + PV + ones-li (32x32x16 f16) ----
    __builtin_amdgcn_s_setprio(1);
#pragma unroll
    for (int kk = 0; kk < 2; kk++)
#pragma unroll
      for (int s = 0; s < 2; s++) {
        u32x2 r0 = plswap(as_u32(pe[kk][4 * s + 0]), as_u32(pe[kk][4 * s + 2]));
        u32x2 r1 = plswap(as_u32(pe[kk][4 * s + 1]), as_u32(pe[kk][4 * s + 3]));
        f16x8 pa = pack4(as_f16x2(r0.x), as_f16x2(r1.x), as_f16x2(r0.y), as_f16x2(r1.y));
        const int ksub = kk * 2 + s;
        f16x8 v0 = *(const f16x8*)&bV[(0 * 4 + ksub) * 512 + lane * 8];
        f16x8 v1 = *(const f16x8*)&bV[(1 * 4 + ksub) * 512 + lane * 8];
        cacc[0] = __builtin_amdgcn_mfma_f32_32x32x16_f16(pa, v0, cacc[0], 0, 0, 0);
        cacc[1] = __builtin_amdgcn_mfma_f32_32x32x16_f16(pa, v1, cacc[1], 0, 0, 0);
        caccl = __builtin_amdgcn_mfma_f32_32x32x16_f16(pa, onesv, caccl, 0, 0, 0);
      }
    __builtin_amdgcn_s_setprio(0);

    // counted wait + RAW barrier: kt+1's stage landed, kt+2's stays in flight.
    asm volatile("s_waitcnt vmcnt(2) lgkmcnt(0)" ::: "memory");
    __builtin_amdgcn_sched_barrier(0);
    __builtin_amdgcn_s_barrier();
    __builtin_amdgcn_sched_barrier(0);
    cur = (cur == 2) ? 0 : cur + 1;
    nxt = (nxt == 2) ? 0 : nxt + 1;
  }
#undef STAGE

  // li: caccl rows == cacc rows -> no shuffles at all
  float linv[16];
#pragma unroll
  for (int r = 0; r < 16; r++) linv[r] = 1.0f / caccl[r];

  // epilogue: scalar scatter into the 16x16 FRAGMENT-MAJOR ctxf for gemm_o
#pragma unroll
  for (int dt = 0; dt < 2; dt++) {
    const int c = colbase + dt * 32 + l31;  // global feature col 0..511
    const long ckb = (long)(c >> 6);
    const int cbit = (c >> 5) & 1;
    const int lane16 = ((c >> 3) & 3) * 16;
    const int e = c & 7;
#pragma unroll
    for (int r = 0; r < 16; r++) {
      long row = qrow0 + (r & 3) + 8 * (r >> 2) + 4 * hi;
      long off = ((((row >> 7) * 8 + ckb) * 16 + ((row >> 4) & 7) * 2 + cbit) * 64 +
                  lane16 + (row & 15)) * 8 + e;
      ctxf[off] = f2bf(cacc[dt][r] * linv[r]);
    }
  }
}

extern "C" void kernel_launch(void* const* d_in, const int* in_sizes, int n_in,
                              void* d_out, int out_size, void* d_ws, size_t ws_size,
                              hipStream_t stream) {
  (void)in_sizes; (void)n_in; (void)out_size; (void)ws_size;
  const float* x = (const float*)d_in[0];
  const float* Wq = (const float*)d_in[1];
  const float* bq = (const float*)d_in[2];
  const float* Wkv = (const float*)d_in[3];
  const float* bkv = (const float*)d_in[4];
  const float* Wo = (const float*)d_in[5];
  const float* bo = (const float*)d_in[6];

  char* ws = (char*)d_ws;
  unsigned short* xf     = (unsigned short*)(ws);             // 16 MiB (reused as ctxf)
  unsigned short* Wqf    = (unsigned short*)(ws + 16777216);  // 512 KiB
  unsigned short* Wkvf   = (unsigned short*)(ws + 17301504);  // 512 KiB
  unsigned short* Wof    = (unsigned short*)(ws + 17825792);  // 512 KiB
  unsigned short* Qn_bf  = (unsigned short*)(ws + 18350080);  // 16 MiB
  unsigned short* Kf     = (unsigned short*)(ws + 35127296);  // 16 MiB
  unsigned short* Vf     = (unsigned short*)(ws + 51904512);  // 16 MiB
  unsigned short* ctxf   = xf;  // x dead after gemm_qkv

  cvt_all<<<8960, 256, 0, stream>>>(x, Wq, Wkv, Wo, xf, Wqf, Wkvf, Wof);

  gemm_qkv<<<dim3(128, 8), 256, 0, stream>>>(xf, Wqf, Wkvf, bq, bkv, Qn_bf, Kf, Vf);

  attn_cos<<<512, 512, 0, stream>>>(Qn_bf, Kf, Vf, ctxf);

  gemm_o<<<dim3(128, 4), 256, 0, stream>>>(ctxf, Wof, bo, (float*)d_out);
}